// Round 1
// baseline (4615.607 us; speedup 1.0000x reference)
//
#include <hip/hip_runtime.h>
#include <math.h>

#define N_NODES 50000
#define IN_DIMC 2000
#define FF_DIM 2048
#define EPSV 1e-5f
#define SCAN_B 1024

// ------------------------------------------------------------------
// utility
// ------------------------------------------------------------------
__global__ void k_zero_i32(int* p, int n) {
    int i = blockIdx.x * blockDim.x + threadIdx.x;
    if (i < n) p[i] = 0;
}

__global__ void k_hist(const int* __restrict__ dst, int* __restrict__ deg, int E, int n) {
    int i = blockIdx.x * blockDim.x + threadIdx.x;
    if (i < E + n) {
        int d = (i < E) ? dst[i] : (i - E);   // self-loops appended
        atomicAdd(&deg[d], 1);
    }
}

__global__ __launch_bounds__(1024) void k_scan1(const int* __restrict__ deg, int* __restrict__ rstart,
                                                int* __restrict__ part, int n) {
    __shared__ int lds[SCAN_B];
    int t = threadIdx.x;
    int base = blockIdx.x * SCAN_B;
    int v = (base + t < n) ? deg[base + t] : 0;
    lds[t] = v;
    __syncthreads();
    for (int o = 1; o < SCAN_B; o <<= 1) {
        int add = (t >= o) ? lds[t - o] : 0;
        __syncthreads();
        lds[t] += add;
        __syncthreads();
    }
    if (base + t < n) rstart[base + t] = lds[t] - v;  // exclusive
    if (t == SCAN_B - 1) part[blockIdx.x] = lds[t];
}

__global__ void k_scan2(int* part, int nb) {
    if (threadIdx.x == 0 && blockIdx.x == 0) {
        int s = 0;
        for (int i = 0; i < nb; i++) { int v = part[i]; part[i] = s; s += v; }
    }
}

__global__ void k_scan3(int* rstart, const int* __restrict__ part, int n) {
    int i = blockIdx.x * blockDim.x + threadIdx.x;
    if (i < n) rstart[i] += part[i / SCAN_B];
}

__global__ void k_scatter(const int* __restrict__ src, const int* __restrict__ dst,
                          const int* __restrict__ rstart, int* __restrict__ cursor,
                          int* __restrict__ csr_src, int E, int n) {
    int i = blockIdx.x * blockDim.x + threadIdx.x;
    if (i < E + n) {
        int s, d;
        if (i < E) { s = src[i]; d = dst[i]; } else { s = i - E; d = s; }
        int pos = rstart[d] + atomicAdd(&cursor[d], 1);
        csr_src[pos] = s;
    }
}

// ------------------------------------------------------------------
// generic fp32 GEMM: C[M,N] = A[M,K] @ B[K,N] (+bias)
// 256 threads; thread tile 8 rows (split 2x4) x (CS*4) cols (split CS x4).
// Split-half fragment layout keeps LDS reads broadcast/2-way (free).
// ------------------------------------------------------------------
template<int BM, int BN, int BK, int CS>
__global__ __launch_bounds__(256) void k_gemm(const float* __restrict__ A, const float* __restrict__ B,
                                              const float* __restrict__ bias, float* __restrict__ C,
                                              int M, int N, int K) {
    __shared__ float As[BK][BM + 4];
    __shared__ float Bs[BK][BN + 4];
    int tid = threadIdx.x;
    long m0 = (long)blockIdx.x * BM;
    int n0 = blockIdx.y * BN;
    int tc = tid & 15, tr = tid >> 4;
    float acc[2][CS][4][4] = {};
    for (int k0 = 0; k0 < K; k0 += BK) {
        constexpr int APASS = BM * BK / 1024;
#pragma unroll
        for (int p = 0; p < APASS; p++) {
            int f4 = tid + p * 256;
            int kq = f4 % (BK / 4);
            int row = f4 / (BK / 4);
            long gm = m0 + row;
            float4 a = {0.f, 0.f, 0.f, 0.f};
            if (gm < M) a = *(const float4*)&A[gm * K + k0 + kq * 4];
            As[kq * 4 + 0][row] = a.x;
            As[kq * 4 + 1][row] = a.y;
            As[kq * 4 + 2][row] = a.z;
            As[kq * 4 + 3][row] = a.w;
        }
        constexpr int BPASS = BK * BN / 1024;
#pragma unroll
        for (int p = 0; p < BPASS; p++) {
            int f4 = tid + p * 256;
            int c4 = f4 % (BN / 4);
            int kr = f4 / (BN / 4);
            int gc = n0 + c4 * 4;
            const float* brow = &B[(size_t)(k0 + kr) * N];
            float4 b;
            if ((N & 3) == 0 && gc + 3 < N) {
                b = *(const float4*)&brow[gc];
            } else {
                float t0[4] = {0.f, 0.f, 0.f, 0.f};
                for (int i = 0; i < 4; i++)
                    if (gc + i < N) t0[i] = brow[gc + i];
                b.x = t0[0]; b.y = t0[1]; b.z = t0[2]; b.w = t0[3];
            }
            *(float4*)&Bs[kr][c4 * 4] = b;
        }
        __syncthreads();
#pragma unroll
        for (int k = 0; k < BK; k++) {
            float av[2][4], bv[CS][4];
            float4 a0 = *(const float4*)&As[k][4 * tr];
            float4 a1 = *(const float4*)&As[k][BM / 2 + 4 * tr];
            av[0][0] = a0.x; av[0][1] = a0.y; av[0][2] = a0.z; av[0][3] = a0.w;
            av[1][0] = a1.x; av[1][1] = a1.y; av[1][2] = a1.z; av[1][3] = a1.w;
            float4 b0 = *(const float4*)&Bs[k][4 * tc];
            bv[0][0] = b0.x; bv[0][1] = b0.y; bv[0][2] = b0.z; bv[0][3] = b0.w;
            if (CS == 2) {
                float4 b1 = *(const float4*)&Bs[k][BN / 2 + 4 * tc];
                bv[1][0] = b1.x; bv[1][1] = b1.y; bv[1][2] = b1.z; bv[1][3] = b1.w;
            }
#pragma unroll
            for (int rs = 0; rs < 2; rs++)
#pragma unroll
                for (int cs = 0; cs < CS; cs++)
#pragma unroll
                    for (int i = 0; i < 4; i++)
#pragma unroll
                        for (int j = 0; j < 4; j++)
                            acc[rs][cs][i][j] += av[rs][i] * bv[cs][j];
        }
        __syncthreads();
    }
#pragma unroll
    for (int rs = 0; rs < 2; rs++)
        for (int i = 0; i < 4; i++) {
            long gm = m0 + rs * (BM / 2) + 4 * tr + i;
            if (gm >= M) continue;
            for (int cs = 0; cs < CS; cs++)
                for (int j = 0; j < 4; j++) {
                    int gc = n0 + cs * (BN / 2) + 4 * tc + j;
                    if (gc >= N) continue;
                    float v = acc[rs][cs][i][j];
                    if (bias) v += bias[gc];
                    C[gm * N + gc] = v;
                }
        }
}

// ------------------------------------------------------------------
// per-(node,head) attention logits: al = sum_d h[n,h,d] * a[h,d]
// one wave per (node, head)
// ------------------------------------------------------------------
template<int H, int D>
__global__ void k_al(const float* __restrict__ h, const float* __restrict__ a_src,
                     const float* __restrict__ a_dst, float* __restrict__ als,
                     float* __restrict__ ald, int n) {
    long w = ((long)blockIdx.x * blockDim.x + threadIdx.x) >> 6;
    int lane = threadIdx.x & 63;
    long nn = w / H;
    int hh = (int)(w % H);
    if (nn >= n) return;
    float v = 0.f, u = 0.f;
    if (lane < D) {
        float hv = h[nn * (H * D) + hh * D + lane];
        v = hv * a_src[hh * D + lane];
        u = hv * a_dst[hh * D + lane];
    }
#pragma unroll
    for (int o = 32; o > 0; o >>= 1) {
        v += __shfl_xor(v, o, 64);
        u += __shfl_xor(u, o, 64);
    }
    if (lane == 0) { als[nn * H + hh] = v; ald[nn * H + hh] = u; }
}

// ------------------------------------------------------------------
// GAT segment-softmax + aggregation, CSR by dst, one block per node.
// Softmax computed WITHOUT max subtraction (shift-invariant; logits
// bounded ~|8| for this data, exp safe in fp32; +1e-16 denom matches ref
// to ~1e-14 rel). Self-loop guarantees wsum > 0.
// ------------------------------------------------------------------
template<int H, int D, bool DO_ELU>
__global__ __launch_bounds__(256) void k_gat_agg(const float* __restrict__ h, const float* __restrict__ als,
                                                 const float* __restrict__ ald, const float* __restrict__ bias,
                                                 const int* __restrict__ rstart, const int* __restrict__ deg,
                                                 const int* __restrict__ csr_src, float* __restrict__ out) {
    const int CH = 64;
    __shared__ float wbuf[CH][H];
    __shared__ int sbuf[CH];
    int n = blockIdx.x;
    int tid = threadIdx.x;
    int hh = (D == 64) ? (tid >> 6) : (tid / D);
    int d = (D == 64) ? (tid & 63) : (tid % D);
    bool act = tid < H * D;
    int beg = rstart[n];
    int cnt = deg[n];
    float acc = 0.f, wsum = 0.f;
    for (int c0 = 0; c0 < cnt; c0 += CH) {
        int rem = min(CH, cnt - c0);
        if (tid < CH * H) {
            int ei = tid & (CH - 1);
            int h2 = tid >> 6;  // CH==64
            if (ei < rem) {
                int s = csr_src[beg + c0 + ei];
                if (h2 == 0) sbuf[ei] = s;
                float l = als[s * H + h2] + ald[n * H + h2];
                l = (l > 0.f) ? l : 0.2f * l;  // leaky_relu 0.2
                wbuf[ei][h2] = __expf(l);
            }
        }
        __syncthreads();
        if (act) {
            for (int ei = 0; ei < rem; ei++) {
                int s = sbuf[ei];
                float w = wbuf[ei][hh];
                wsum += w;
                acc += w * h[(size_t)s * (H * D) + hh * D + d];
            }
        }
        __syncthreads();
    }
    if (act) {
        float v = acc / (wsum + 1e-16f) + bias[hh * D + d];
        if (DO_ELU) v = (v > 0.f) ? v : expm1f(v);
        out[(size_t)n * (H * D) + hh * D + d] = v;
    }
}

// ------------------------------------------------------------------
// residual + LayerNorm over 64-dim rows, one wave per row
// ------------------------------------------------------------------
__global__ void k_ln(const float* __restrict__ x, const float* __restrict__ y,
                     const float* __restrict__ g, const float* __restrict__ b,
                     float* __restrict__ out, int n) {
    long w = ((long)blockIdx.x * blockDim.x + threadIdx.x) >> 6;
    int lane = threadIdx.x & 63;
    if (w >= n) return;
    float v = x[w * 64 + lane] + y[w * 64 + lane];
    float s = v;
#pragma unroll
    for (int o = 32; o > 0; o >>= 1) s += __shfl_xor(s, o, 64);
    float mu = s * (1.f / 64.f);
    float dv = v - mu;
    float q = dv * dv;
#pragma unroll
    for (int o = 32; o > 0; o >>= 1) q += __shfl_xor(q, o, 64);
    float var = q * (1.f / 64.f);
    out[w * 64 + lane] = dv * rsqrtf(var + EPSV) * g[lane] + b[lane];
}

// ------------------------------------------------------------------
// fused FF: out = relu(x @ Wf1 + bf1) @ Wf2 + bf2, never materializing
// the [n, 2048] hidden. Block = 64 rows x 64 cols, j-chunks of 64.
// ------------------------------------------------------------------
__global__ __launch_bounds__(256) void k_ff(const float* __restrict__ x,
                                            const float* __restrict__ Wf1, const float* __restrict__ bf1,
                                            const float* __restrict__ Wf2, const float* __restrict__ bf2,
                                            float* __restrict__ out, int n) {
    __shared__ float xsT[64][65];  // xsT[k][r]
    __shared__ float w1s[64][65];  // w1s[k][c]
    __shared__ float tsT[64][65];  // tsT[j][r]
    __shared__ float w2s[64][65];  // w2s[j][c]
    int tid = threadIdx.x;
    long row0 = (long)blockIdx.x * 64;
    int tc = tid & 15, tr = tid >> 4;
    {
        int c4 = (tid & 15) * 4;
        int r = tid >> 4;
#pragma unroll
        for (int p = 0; p < 4; p++) {
            int rr = r + p * 16;
            float4 a = {0.f, 0.f, 0.f, 0.f};
            if (row0 + rr < n) a = *(const float4*)&x[(row0 + rr) * 64 + c4];
            xsT[c4 + 0][rr] = a.x; xsT[c4 + 1][rr] = a.y;
            xsT[c4 + 2][rr] = a.z; xsT[c4 + 3][rr] = a.w;
        }
    }
    float acc[4][4] = {};
    for (int j0 = 0; j0 < FF_DIM; j0 += 64) {
        {
            int c4 = (tid & 15) * 4;
            int k = tid >> 4;
#pragma unroll
            for (int p = 0; p < 4; p++) {
                int kk = k + p * 16;
                *(float4*)&w1s[kk][c4] = *(const float4*)&Wf1[(size_t)kk * FF_DIM + j0 + c4];
                *(float4*)&w2s[kk][c4] = *(const float4*)&Wf2[(size_t)(j0 + kk) * 64 + c4];
            }
        }
        __syncthreads();
        float tt[4][4];
        {
            float4 bb = *(const float4*)&bf1[j0 + 4 * tc];
#pragma unroll
            for (int i = 0; i < 4; i++) { tt[i][0] = bb.x; tt[i][1] = bb.y; tt[i][2] = bb.z; tt[i][3] = bb.w; }
#pragma unroll
            for (int k = 0; k < 64; k++) {
                float4 a = *(const float4*)&xsT[k][4 * tr];
                float4 b = *(const float4*)&w1s[k][4 * tc];
                float av[4] = {a.x, a.y, a.z, a.w}, bvv[4] = {b.x, b.y, b.z, b.w};
#pragma unroll
                for (int i = 0; i < 4; i++)
#pragma unroll
                    for (int j = 0; j < 4; j++) tt[i][j] += av[i] * bvv[j];
            }
        }
#pragma unroll
        for (int i = 0; i < 4; i++)
            for (int j = 0; j < 4; j++)
                tsT[4 * tc + j][4 * tr + i] = fmaxf(tt[i][j], 0.f);
        __syncthreads();
#pragma unroll
        for (int k = 0; k < 64; k++) {
            float4 a = *(const float4*)&tsT[k][4 * tr];
            float4 b = *(const float4*)&w2s[k][4 * tc];
            float av[4] = {a.x, a.y, a.z, a.w}, bvv[4] = {b.x, b.y, b.z, b.w};
#pragma unroll
            for (int i = 0; i < 4; i++)
#pragma unroll
                for (int j = 0; j < 4; j++) acc[i][j] += av[i] * bvv[j];
        }
        __syncthreads();
    }
    float4 b2 = *(const float4*)&bf2[4 * tc];
    float bv2[4] = {b2.x, b2.y, b2.z, b2.w};
#pragma unroll
    for (int i = 0; i < 4; i++) {
        long gr = row0 + 4 * tr + i;
        if (gr < n) {
            float4 o;
            o.x = acc[i][0] + bv2[0]; o.y = acc[i][1] + bv2[1];
            o.z = acc[i][2] + bv2[2]; o.w = acc[i][3] + bv2[3];
            *(float4*)&out[gr * 64 + 4 * tc] = o;
        }
    }
}

// ------------------------------------------------------------------
extern "C" void kernel_launch(void* const* d_in, const int* in_sizes, int n_in,
                              void* d_out, int out_size, void* d_ws, size_t ws_size,
                              hipStream_t stream) {
    const float* x = (const float*)d_in[0];
    const int* esrc = (const int*)d_in[1];
    const int* edst = (const int*)d_in[2];
    const float* W1 = (const float*)d_in[3];
    const float* as1 = (const float*)d_in[4];
    const float* ad1 = (const float*)d_in[5];
    const float* b1 = (const float*)d_in[6];
    const float* W2 = (const float*)d_in[7];
    const float* as2 = (const float*)d_in[8];
    const float* ad2 = (const float*)d_in[9];
    const float* b2 = (const float*)d_in[10];
    // d_in[11] t_Wq, d_in[12] t_Wk, d_in[14] t_bq, d_in[15] t_bk: dead code
    // (seq_len==1 -> softmax over a single logit == 1 -> attn = v)
    const float* tWv = (const float*)d_in[13];
    const float* tbv = (const float*)d_in[16];
    const float* tWo = (const float*)d_in[17];
    const float* tbo = (const float*)d_in[18];
    const float* tg1 = (const float*)d_in[19];
    const float* tb1 = (const float*)d_in[20];
    const float* tWf1 = (const float*)d_in[21];
    const float* tbf1 = (const float*)d_in[22];
    const float* tWf2 = (const float*)d_in[23];
    const float* tbf2 = (const float*)d_in[24];
    const float* tg2 = (const float*)d_in[25];
    const float* tb2 = (const float*)d_in[26];
    const float* W3 = (const float*)d_in[27];
    const float* as3 = (const float*)d_in[28];
    const float* ad3 = (const float*)d_in[29];
    const float* b3 = (const float*)d_in[30];

    const int n = N_NODES;
    const int E = in_sizes[1];
    const int ET = E + n;

    // workspace layout (all offsets 16B-aligned); peak ~164 MB
    float* fw = (float*)d_ws;
    float* h1 = fw;                  // [n,256]
    float* agg1 = h1 + 12800000;     // [n,256]
    float* bufA = agg1 + 12800000;   // [n,64]
    float* bufB = bufA + 3200000;    // [n,64]
    float* bufC = bufB + 3200000;    // [n,64]
    float* bufD = bufC + 3200000;    // [n,64]
    float* als = bufD + 3200000;     // [n,4]
    float* ald = als + 200000;       // [n,4]
    float* h3 = h1;                  // [n,25] reuses h1 (dead by then)
    int* deg = (int*)(ald + 200000);
    int* rstart = deg + 50016;
    int* cursor = rstart + 50016;
    int* part = cursor + 50016;
    int* csr = part + 64;            // [E+n]

    float* outAdt = (float*)d_out;                 // [n,25]
    float* outFused = outAdt + (size_t)n * 25;     // [n,64]

    // ---- CSR build (dst-sorted adjacency incl. self-loops) ----
    k_zero_i32<<<(150048 + 255) / 256, 256, 0, stream>>>(deg, 150048);  // deg,rstart,cursor
    k_hist<<<(ET + 255) / 256, 256, 0, stream>>>(edst, deg, E, n);
    int nsb = (n + SCAN_B - 1) / SCAN_B;
    k_scan1<<<nsb, SCAN_B, 0, stream>>>(deg, rstart, part, n);
    k_scan2<<<1, 64, 0, stream>>>(part, nsb);
    k_scan3<<<(n + 255) / 256, 256, 0, stream>>>(rstart, part, n);
    k_scatter<<<(ET + 255) / 256, 256, 0, stream>>>(esrc, edst, rstart, cursor, csr, E, n);

    // ---- GAT layer 1 (heads=4, D=64) ----
    k_gemm<128, 128, 8, 2><<<dim3((n + 127) / 128, 2), 256, 0, stream>>>(x, W1, nullptr, h1, n, 256, IN_DIMC);
    k_al<4, 64><<<n, 256, 0, stream>>>(h1, as1, ad1, als, ald, n);
    k_gat_agg<4, 64, true><<<n, 256, 0, stream>>>(h1, als, ald, b1, rstart, deg, csr, agg1);

    // ---- GAT layer 2 (heads=1, D=64) ----
    k_gemm<128, 64, 16, 1><<<dim3((n + 127) / 128, 1), 256, 0, stream>>>(agg1, W2, nullptr, bufA, n, 64, 256);
    k_al<1, 64><<<(n + 3) / 4, 256, 0, stream>>>(bufA, as2, ad2, als, ald, n);
    k_gat_agg<1, 64, true><<<n, 64, 0, stream>>>(bufA, als, ald, b2, rstart, deg, csr, bufB);

    // ---- Transformer encoder x2 (q,k dead; attn = v@Wo+bo) ----
    float* xin = bufB;
    for (int l = 0; l < 2; l++) {
        const float* Wv = tWv + (size_t)l * 64 * 64;
        const float* bv = tbv + (size_t)l * 64;
        const float* Wo = tWo + (size_t)l * 64 * 64;
        const float* bo = tbo + (size_t)l * 64;
        const float* g1p = tg1 + (size_t)l * 64;
        const float* b1p = tb1 + (size_t)l * 64;
        const float* Wf1 = tWf1 + (size_t)l * 64 * FF_DIM;
        const float* bf1 = tbf1 + (size_t)l * FF_DIM;
        const float* Wf2 = tWf2 + (size_t)l * FF_DIM * 64;
        const float* bf2 = tbf2 + (size_t)l * 64;
        const float* g2p = tg2 + (size_t)l * 64;
        const float* b2p = tb2 + (size_t)l * 64;
        k_gemm<128, 64, 16, 1><<<dim3((n + 127) / 128, 1), 256, 0, stream>>>(xin, Wv, bv, bufC, n, 64, 64);
        k_gemm<128, 64, 16, 1><<<dim3((n + 127) / 128, 1), 256, 0, stream>>>(bufC, Wo, bo, bufD, n, 64, 64);
        k_ln<<<(n + 3) / 4, 256, 0, stream>>>(xin, bufD, g1p, b1p, bufA, n);
        k_ff<<<(n + 63) / 64, 256, 0, stream>>>(bufA, Wf1, bf1, Wf2, bf2, bufC, n);
        float* xout = (l == 1) ? outFused : bufB;
        k_ln<<<(n + 3) / 4, 256, 0, stream>>>(bufA, bufC, g2p, b2p, xout, n);
        xin = xout;
    }

    // ---- GAT ADT head (heads=1, D=25, no ELU) ----
    k_gemm<128, 64, 16, 1><<<dim3((n + 127) / 128, 1), 256, 0, stream>>>(outFused, W3, nullptr, h3, n, 25, 64);
    k_al<1, 25><<<(n + 3) / 4, 256, 0, stream>>>(h3, as3, ad3, als, ald, n);
    k_gat_agg<1, 25, false><<<n, 64, 0, stream>>>(h3, als, ald, b3, rstart, deg, csr, outAdt);
}

// Round 3
// 1626.009 us; speedup vs baseline: 2.8386x; 2.8386x over previous
//
#include <hip/hip_runtime.h>
#include <math.h>

#define N_NODES 50000
#define IN_DIMC 2000
#define FF_DIM 2048
#define EPSV 1e-5f
#define SCAN_B 1024

typedef __attribute__((ext_vector_type(8))) short sh8;
typedef __attribute__((ext_vector_type(4))) short sh4;
typedef __attribute__((ext_vector_type(4))) float f32x4;

// truncation split: f = hi + lo (+ O(2^-16) rel); cheap (no rounding carries)
__device__ __forceinline__ void splitf(float f, unsigned short& h, unsigned short& l) {
    unsigned u = __float_as_uint(f);
    h = (unsigned short)(u >> 16);
    float fh = __uint_as_float(u & 0xFFFF0000u);
    l = (unsigned short)(__float_as_uint(f - fh) >> 16);
}

// ------------------------------------------------------------------
// utility / CSR build
// ------------------------------------------------------------------
__global__ void k_zero_i32(int* p, int n) {
    int i = blockIdx.x * blockDim.x + threadIdx.x;
    if (i < n) p[i] = 0;
}

__global__ void k_hist(const int* __restrict__ dst, int* __restrict__ deg, int E, int n) {
    int i = blockIdx.x * blockDim.x + threadIdx.x;
    if (i < E + n) {
        int d = (i < E) ? dst[i] : (i - E);
        atomicAdd(&deg[d], 1);
    }
}

__global__ __launch_bounds__(1024) void k_scan1(const int* __restrict__ deg, int* __restrict__ rstart,
                                                int* __restrict__ part, int n) {
    __shared__ int lds[SCAN_B];
    int t = threadIdx.x;
    int base = blockIdx.x * SCAN_B;
    int v = (base + t < n) ? deg[base + t] : 0;
    lds[t] = v;
    __syncthreads();
    for (int o = 1; o < SCAN_B; o <<= 1) {
        int add = (t >= o) ? lds[t - o] : 0;
        __syncthreads();
        lds[t] += add;
        __syncthreads();
    }
    if (base + t < n) rstart[base + t] = lds[t] - v;
    if (t == SCAN_B - 1) part[blockIdx.x] = lds[t];
}

__global__ void k_scan2(int* part, int nb) {
    if (threadIdx.x == 0 && blockIdx.x == 0) {
        int s = 0;
        for (int i = 0; i < nb; i++) { int v = part[i]; part[i] = s; s += v; }
    }
}

__global__ void k_scan3(int* rstart, const int* __restrict__ part, int n) {
    int i = blockIdx.x * blockDim.x + threadIdx.x;
    if (i < n) rstart[i] += part[i / SCAN_B];
}

__global__ void k_scatter(const int* __restrict__ src, const int* __restrict__ dst,
                          const int* __restrict__ rstart, int* __restrict__ cursor,
                          int* __restrict__ csr_src, int E, int n) {
    int i = blockIdx.x * blockDim.x + threadIdx.x;
    if (i < E + n) {
        int s, d;
        if (i < E) { s = src[i]; d = dst[i]; } else { s = i - E; d = s; }
        int pos = rstart[d] + atomicAdd(&cursor[d], 1);
        csr_src[pos] = s;
    }
}

// ------------------------------------------------------------------
// weight pre-split: W [K][N] fp32 -> Wt_hi/lo [N][K] bf16
// ------------------------------------------------------------------
__global__ void k_wsplit(const float* __restrict__ W, short* __restrict__ oh,
                         short* __restrict__ ol, int K, int N) {
    int i = blockIdx.x * blockDim.x + threadIdx.x;
    if (i < K * N) {
        int k = i / N, c = i - k * N;
        unsigned short h, l;
        splitf(W[i], h, l);
        oh[(size_t)c * K + k] = (short)h;
        ol[(size_t)c * K + k] = (short)l;
    }
}

// ------------------------------------------------------------------
// split-bf16 MFMA GEMM: C[M,N] = A[M,K] @ B[K,N]
// A fp32 (split during staging); B pre-split [N][K] bf16 hi/lo.
// 128x128 tile, BK=64, 4 waves (2x2, 64x64 each). 72 KB LDS -> 2 blk/CU.
// 144B LDS rows: frag reads <=2-way bank alias (free, m136).
// ------------------------------------------------------------------
__global__ __launch_bounds__(256, 2) void k_gemm_sb(const float* __restrict__ A,
                                                    const short* __restrict__ Bth,
                                                    const short* __restrict__ Btl,
                                                    float* __restrict__ C, int M, int N, int K) {
    __shared__ short lds[36864];
    short* Ah = lds;            // [128][72]
    short* Al = lds + 9216;
    short* Bh = lds + 18432;    // [128 cols][72]
    short* Bl = lds + 27648;
    int tid = threadIdx.x;
    int wave = tid >> 6, lane = tid & 63;
    int wm = wave & 1, wn = wave >> 1;
    int l15 = lane & 15, l4 = lane >> 4;
    long m0 = (long)blockIdx.x * 128;
    int n0 = blockIdx.y * 128;
    f32x4 acc[4][4] = {};
    int ktiles = (K + 63) >> 6;
    for (int kt = 0; kt < ktiles; kt++) {
        int k0 = kt << 6;
#pragma unroll
        for (int p = 0; p < 8; p++) {           // stage A: 128x64 fp32 -> hi/lo
            int f4 = tid + p * 256;
            int row = f4 >> 4, kq = f4 & 15;
            long gm = m0 + row;
            int gk = k0 + kq * 4;
            float4 a = {0.f, 0.f, 0.f, 0.f};
            if (gm < M && gk < K) a = *(const float4*)&A[gm * K + gk];
            unsigned short h0, h1, h2, h3, l0, l1, l2, l3;
            splitf(a.x, h0, l0); splitf(a.y, h1, l1);
            splitf(a.z, h2, l2); splitf(a.w, h3, l3);
            sh4 hv = {(short)h0, (short)h1, (short)h2, (short)h3};
            sh4 lv = {(short)l0, (short)l1, (short)l2, (short)l3};
            *(sh4*)&Ah[row * 72 + kq * 4] = hv;
            *(sh4*)&Al[row * 72 + kq * 4] = lv;
        }
#pragma unroll
        for (int p = 0; p < 4; p++) {           // stage B: 128 cols x 64 k bf16
            int u = tid + p * 256;
            int col = u >> 3, kq8 = u & 7;
            int gk = k0 + kq8 * 8;
            int gc = n0 + col;
            sh8 bh8 = {0, 0, 0, 0, 0, 0, 0, 0}, bl8 = {0, 0, 0, 0, 0, 0, 0, 0};
            if (gk < K) {
                bh8 = *(const sh8*)&Bth[(size_t)gc * K + gk];
                bl8 = *(const sh8*)&Btl[(size_t)gc * K + gk];
            }
            *(sh8*)&Bh[col * 72 + kq8 * 8] = bh8;
            *(sh8*)&Bl[col * 72 + kq8 * 8] = bl8;
        }
        __syncthreads();
#pragma unroll
        for (int kf = 0; kf < 2; kf++) {
            sh8 ah[4], alv[4], bh[4], blv[4];
#pragma unroll
            for (int mf = 0; mf < 4; mf++) {
                int off = (wm * 64 + mf * 16 + l15) * 72 + kf * 32 + l4 * 8;
                ah[mf] = *(const sh8*)&Ah[off];
                alv[mf] = *(const sh8*)&Al[off];
            }
#pragma unroll
            for (int nf = 0; nf < 4; nf++) {
                int off = (wn * 64 + nf * 16 + l15) * 72 + kf * 32 + l4 * 8;
                bh[nf] = *(const sh8*)&Bh[off];
                blv[nf] = *(const sh8*)&Bl[off];
            }
#pragma unroll
            for (int mf = 0; mf < 4; mf++)
#pragma unroll
                for (int nf = 0; nf < 4; nf++) {
                    f32x4 c = acc[mf][nf];
                    c = __builtin_amdgcn_mfma_f32_16x16x32_bf16(ah[mf], bh[nf], c, 0, 0, 0);
                    c = __builtin_amdgcn_mfma_f32_16x16x32_bf16(ah[mf], blv[nf], c, 0, 0, 0);
                    c = __builtin_amdgcn_mfma_f32_16x16x32_bf16(alv[mf], bh[nf], c, 0, 0, 0);
                    acc[mf][nf] = c;
                }
        }
        __syncthreads();
    }
#pragma unroll
    for (int mf = 0; mf < 4; mf++)
#pragma unroll
        for (int r = 0; r < 4; r++) {
            long gm = m0 + wm * 64 + mf * 16 + l4 * 4 + r;
            if (gm >= M) continue;
#pragma unroll
            for (int nf = 0; nf < 4; nf++) {
                int gc = n0 + wn * 64 + nf * 16 + l15;
                C[gm * N + gc] = acc[mf][nf][r];
            }
        }
}

// ------------------------------------------------------------------
// fused FF with split-bf16 MFMA: out = relu(x@Wf1+bf1)@Wf2 + bf2.
// 128 rows/block, 32 j-chunks of 64; hidden lives only in LDS (hi/lo).
// W1t [2048][64], W2t [64][2048] pre-split. 72 KB LDS -> 2 blk/CU.
// ------------------------------------------------------------------
__global__ __launch_bounds__(256, 2) void k_ff_mfma(const float* __restrict__ x,
                                                    const short* __restrict__ W1h, const short* __restrict__ W1l,
                                                    const float* __restrict__ bf1,
                                                    const short* __restrict__ W2h, const short* __restrict__ W2l,
                                                    const float* __restrict__ bf2,
                                                    float* __restrict__ out, int n) {
    __shared__ short lds[36864];
    short* Hh = lds;            // [128][72], also aliases staged x
    short* Hl = lds + 9216;
    short* w1h = lds + 18432;   // [64 j][72]
    short* w1l = lds + 23040;
    short* w2h = lds + 27648;   // [64 c][72]
    short* w2l = lds + 32256;
    int tid = threadIdx.x;
    int wave = tid >> 6, lane = tid & 63;
    int wm = wave & 1, wn = wave >> 1;
    int l15 = lane & 15, l4 = lane >> 4;
    long row0 = (long)blockIdx.x * 128;
#pragma unroll
    for (int p = 0; p < 8; p++) {               // stage x [128][64] -> hi/lo LDS
        int f4 = tid + p * 256;
        int row = f4 >> 4, kq = f4 & 15;
        long gr = row0 + row;
        float4 a = {0.f, 0.f, 0.f, 0.f};
        if (gr < n) a = *(const float4*)&x[gr * 64 + kq * 4];
        unsigned short h0, h1, h2, h3, l0, l1, l2, l3;
        splitf(a.x, h0, l0); splitf(a.y, h1, l1);
        splitf(a.z, h2, l2); splitf(a.w, h3, l3);
        sh4 hv = {(short)h0, (short)h1, (short)h2, (short)h3};
        sh4 lv = {(short)l0, (short)l1, (short)l2, (short)l3};
        *(sh4*)&Hh[row * 72 + kq * 4] = hv;
        *(sh4*)&Hl[row * 72 + kq * 4] = lv;
    }
    __syncthreads();
    sh8 xh[4][2], xl[4][2];                     // x A-frags pinned in regs
#pragma unroll
    for (int mf = 0; mf < 4; mf++)
#pragma unroll
        for (int kf = 0; kf < 2; kf++) {
            int off = (wm * 64 + mf * 16 + l15) * 72 + kf * 32 + l4 * 8;
            xh[mf][kf] = *(const sh8*)&Hh[off];
            xl[mf][kf] = *(const sh8*)&Hl[off];
        }
    f32x4 acc2[4][2] = {};
    for (int j0 = 0; j0 < FF_DIM; j0 += 64) {
#pragma unroll
        for (int p = 0; p < 2; p++) {           // stage W1/W2 chunks
            int u = tid + p * 256;
            int cj = u >> 3, kq8 = u & 7;
            *(sh8*)&w1h[cj * 72 + kq8 * 8] = *(const sh8*)&W1h[(size_t)(j0 + cj) * 64 + kq8 * 8];
            *(sh8*)&w1l[cj * 72 + kq8 * 8] = *(const sh8*)&W1l[(size_t)(j0 + cj) * 64 + kq8 * 8];
            *(sh8*)&w2h[cj * 72 + kq8 * 8] = *(const sh8*)&W2h[(size_t)cj * FF_DIM + j0 + kq8 * 8];
            *(sh8*)&w2l[cj * 72 + kq8 * 8] = *(const sh8*)&W2l[(size_t)cj * FF_DIM + j0 + kq8 * 8];
        }
        __syncthreads();   // B1: W staged; x-frag reads (iter0) / prev GEMM2 W-reads done
        f32x4 hacc[4][2] = {};
#pragma unroll
        for (int kf = 0; kf < 2; kf++) {        // GEMM1: H = x @ W1c  (K=64)
            sh8 bh[2], bl[2];
#pragma unroll
            for (int nf = 0; nf < 2; nf++) {
                int off = (wn * 32 + nf * 16 + l15) * 72 + kf * 32 + l4 * 8;
                bh[nf] = *(const sh8*)&w1h[off];
                bl[nf] = *(const sh8*)&w1l[off];
            }
#pragma unroll
            for (int mf = 0; mf < 4; mf++)
#pragma unroll
                for (int nf = 0; nf < 2; nf++) {
                    f32x4 c = hacc[mf][nf];
                    c = __builtin_amdgcn_mfma_f32_16x16x32_bf16(xh[mf][kf], bh[nf], c, 0, 0, 0);
                    c = __builtin_amdgcn_mfma_f32_16x16x32_bf16(xh[mf][kf], bl[nf], c, 0, 0, 0);
                    c = __builtin_amdgcn_mfma_f32_16x16x32_bf16(xl[mf][kf], bh[nf], c, 0, 0, 0);
                    hacc[mf][nf] = c;
                }
        }
#pragma unroll
        for (int mf = 0; mf < 4; mf++)          // bias + relu + split -> H LDS
#pragma unroll
            for (int nf = 0; nf < 2; nf++) {
                int col = wn * 32 + nf * 16 + l15;
                float b1v = bf1[j0 + col];
#pragma unroll
                for (int r = 0; r < 4; r++) {
                    int row = wm * 64 + mf * 16 + l4 * 4 + r;
                    float v = fmaxf(hacc[mf][nf][r] + b1v, 0.f);
                    unsigned short h, l;
                    splitf(v, h, l);
                    Hh[row * 72 + col] = (short)h;
                    Hl[row * 72 + col] = (short)l;
                }
            }
        __syncthreads();   // B2: H visible
#pragma unroll
        for (int kf = 0; kf < 2; kf++) {        // GEMM2: acc2 += H @ W2c (K=64)
            sh8 ah[4], alv[4], bh[2], bl[2];
#pragma unroll
            for (int mf = 0; mf < 4; mf++) {
                int off = (wm * 64 + mf * 16 + l15) * 72 + kf * 32 + l4 * 8;
                ah[mf] = *(const sh8*)&Hh[off];
                alv[mf] = *(const sh8*)&Hl[off];
            }
#pragma unroll
            for (int nf = 0; nf < 2; nf++) {
                int off = (wn * 32 + nf * 16 + l15) * 72 + kf * 32 + l4 * 8;
                bh[nf] = *(const sh8*)&w2h[off];
                bl[nf] = *(const sh8*)&w2l[off];
            }
#pragma unroll
            for (int mf = 0; mf < 4; mf++)
#pragma unroll
                for (int nf = 0; nf < 2; nf++) {
                    f32x4 c = acc2[mf][nf];
                    c = __builtin_amdgcn_mfma_f32_16x16x32_bf16(ah[mf], bh[nf], c, 0, 0, 0);
                    c = __builtin_amdgcn_mfma_f32_16x16x32_bf16(ah[mf], bl[nf], c, 0, 0, 0);
                    c = __builtin_amdgcn_mfma_f32_16x16x32_bf16(alv[mf], bh[nf], c, 0, 0, 0);
                    acc2[mf][nf] = c;
                }
        }
        __syncthreads();   // B3: GEMM2 H/W reads done before next staging
    }
#pragma unroll
    for (int mf = 0; mf < 4; mf++)
#pragma unroll
        for (int r = 0; r < 4; r++) {
            long gr = row0 + wm * 64 + mf * 16 + l4 * 4 + r;
            if (gr >= n) continue;
#pragma unroll
            for (int nf = 0; nf < 2; nf++) {
                int gc = wn * 32 + nf * 16 + l15;
                out[gr * 64 + gc] = acc2[mf][nf][r] + bf2[gc];
            }
        }
}

// ------------------------------------------------------------------
// generic fp32 GEMM (kept for small GEMMs: K<=256, N<=64)
// ------------------------------------------------------------------
template<int BM, int BN, int BK, int CS>
__global__ __launch_bounds__(256) void k_gemm(const float* __restrict__ A, const float* __restrict__ B,
                                              const float* __restrict__ bias, float* __restrict__ C,
                                              int M, int N, int K) {
    __shared__ float As[BK][BM + 4];
    __shared__ float Bs[BK][BN + 4];
    int tid = threadIdx.x;
    long m0 = (long)blockIdx.x * BM;
    int n0 = blockIdx.y * BN;
    int tc = tid & 15, tr = tid >> 4;
    float acc[2][CS][4][4] = {};
    for (int k0 = 0; k0 < K; k0 += BK) {
        constexpr int APASS = BM * BK / 1024;
#pragma unroll
        for (int p = 0; p < APASS; p++) {
            int f4 = tid + p * 256;
            int kq = f4 % (BK / 4);
            int row = f4 / (BK / 4);
            long gm = m0 + row;
            float4 a = {0.f, 0.f, 0.f, 0.f};
            if (gm < M) a = *(const float4*)&A[gm * K + k0 + kq * 4];
            As[kq * 4 + 0][row] = a.x;
            As[kq * 4 + 1][row] = a.y;
            As[kq * 4 + 2][row] = a.z;
            As[kq * 4 + 3][row] = a.w;
        }
        constexpr int BPASS = BK * BN / 1024;
#pragma unroll
        for (int p = 0; p < BPASS; p++) {
            int f4 = tid + p * 256;
            int c4 = f4 % (BN / 4);
            int kr = f4 / (BN / 4);
            int gc = n0 + c4 * 4;
            const float* brow = &B[(size_t)(k0 + kr) * N];
            float4 b;
            if ((N & 3) == 0 && gc + 3 < N) {
                b = *(const float4*)&brow[gc];
            } else {
                float t0[4] = {0.f, 0.f, 0.f, 0.f};
                for (int i = 0; i < 4; i++)
                    if (gc + i < N) t0[i] = brow[gc + i];
                b.x = t0[0]; b.y = t0[1]; b.z = t0[2]; b.w = t0[3];
            }
            *(float4*)&Bs[kr][c4 * 4] = b;
        }
        __syncthreads();
#pragma unroll
        for (int k = 0; k < BK; k++) {
            float av[2][4], bv[CS][4];
            float4 a0 = *(const float4*)&As[k][4 * tr];
            float4 a1 = *(const float4*)&As[k][BM / 2 + 4 * tr];
            av[0][0] = a0.x; av[0][1] = a0.y; av[0][2] = a0.z; av[0][3] = a0.w;
            av[1][0] = a1.x; av[1][1] = a1.y; av[1][2] = a1.z; av[1][3] = a1.w;
            float4 b0 = *(const float4*)&Bs[k][4 * tc];
            bv[0][0] = b0.x; bv[0][1] = b0.y; bv[0][2] = b0.z; bv[0][3] = b0.w;
            if (CS == 2) {
                float4 b1 = *(const float4*)&Bs[k][BN / 2 + 4 * tc];
                bv[1][0] = b1.x; bv[1][1] = b1.y; bv[1][2] = b1.z; bv[1][3] = b1.w;
            }
#pragma unroll
            for (int rs = 0; rs < 2; rs++)
#pragma unroll
                for (int cs = 0; cs < CS; cs++)
#pragma unroll
                    for (int i = 0; i < 4; i++)
#pragma unroll
                        for (int j = 0; j < 4; j++)
                            acc[rs][cs][i][j] += av[rs][i] * bv[cs][j];
        }
        __syncthreads();
    }
#pragma unroll
    for (int rs = 0; rs < 2; rs++)
        for (int i = 0; i < 4; i++) {
            long gm = m0 + rs * (BM / 2) + 4 * tr + i;
            if (gm >= M) continue;
            for (int cs = 0; cs < CS; cs++)
                for (int j = 0; j < 4; j++) {
                    int gc = n0 + cs * (BN / 2) + 4 * tc + j;
                    if (gc >= N) continue;
                    float v = acc[rs][cs][i][j];
                    if (bias) v += bias[gc];
                    C[gm * N + gc] = v;
                }
        }
}

// ------------------------------------------------------------------
// per-(node,head) attention logits
// ------------------------------------------------------------------
template<int H, int D>
__global__ void k_al(const float* __restrict__ h, const float* __restrict__ a_src,
                     const float* __restrict__ a_dst, float* __restrict__ als,
                     float* __restrict__ ald, int n) {
    long w = ((long)blockIdx.x * blockDim.x + threadIdx.x) >> 6;
    int lane = threadIdx.x & 63;
    long nn = w / H;
    int hh = (int)(w % H);
    if (nn >= n) return;
    float v = 0.f, u = 0.f;
    if (lane < D) {
        float hv = h[nn * (H * D) + hh * D + lane];
        v = hv * a_src[hh * D + lane];
        u = hv * a_dst[hh * D + lane];
    }
#pragma unroll
    for (int o = 32; o > 0; o >>= 1) {
        v += __shfl_xor(v, o, 64);
        u += __shfl_xor(u, o, 64);
    }
    if (lane == 0) { als[nn * H + hh] = v; ald[nn * H + hh] = u; }
}

// ------------------------------------------------------------------
// GAT segment-softmax + aggregation (CSR by dst, block per node)
// ------------------------------------------------------------------
template<int H, int D, bool DO_ELU>
__global__ __launch_bounds__(256) void k_gat_agg(const float* __restrict__ h, const float* __restrict__ als,
                                                 const float* __restrict__ ald, const float* __restrict__ bias,
                                                 const int* __restrict__ rstart, const int* __restrict__ deg,
                                                 const int* __restrict__ csr_src, float* __restrict__ out) {
    const int CH = 64;
    __shared__ float wbuf[CH][H];
    __shared__ int sbuf[CH];
    int n = blockIdx.x;
    int tid = threadIdx.x;
    int hh = (D == 64) ? (tid >> 6) : (tid / D);
    int d = (D == 64) ? (tid & 63) : (tid % D);
    bool act = tid < H * D;
    int beg = rstart[n];
    int cnt = deg[n];
    float acc = 0.f, wsum = 0.f;
    for (int c0 = 0; c0 < cnt; c0 += CH) {
        int rem = min(CH, cnt - c0);
        if (tid < CH * H) {
            int ei = tid & (CH - 1);
            int h2 = tid >> 6;
            if (ei < rem) {
                int s = csr_src[beg + c0 + ei];
                if (h2 == 0) sbuf[ei] = s;
                float l = als[s * H + h2] + ald[n * H + h2];
                l = (l > 0.f) ? l : 0.2f * l;
                wbuf[ei][h2] = __expf(l);
            }
        }
        __syncthreads();
        if (act) {
            for (int ei = 0; ei < rem; ei++) {
                int s = sbuf[ei];
                float w = wbuf[ei][hh];
                wsum += w;
                acc += w * h[(size_t)s * (H * D) + hh * D + d];
            }
        }
        __syncthreads();
    }
    if (act) {
        float v = acc / (wsum + 1e-16f) + bias[hh * D + d];
        if (DO_ELU) v = (v > 0.f) ? v : expm1f(v);
        out[(size_t)n * (H * D) + hh * D + d] = v;
    }
}

// ------------------------------------------------------------------
// residual + LayerNorm (64-dim rows, wave per row)
// ------------------------------------------------------------------
__global__ void k_ln(const float* __restrict__ x, const float* __restrict__ y,
                     const float* __restrict__ g, const float* __restrict__ b,
                     float* __restrict__ out, int n) {
    long w = ((long)blockIdx.x * blockDim.x + threadIdx.x) >> 6;
    int lane = threadIdx.x & 63;
    if (w >= n) return;
    float v = x[w * 64 + lane] + y[w * 64 + lane];
    float s = v;
#pragma unroll
    for (int o = 32; o > 0; o >>= 1) s += __shfl_xor(s, o, 64);
    float mu = s * (1.f / 64.f);
    float dv = v - mu;
    float q = dv * dv;
#pragma unroll
    for (int o = 32; o > 0; o >>= 1) q += __shfl_xor(q, o, 64);
    float var = q * (1.f / 64.f);
    out[w * 64 + lane] = dv * rsqrtf(var + EPSV) * g[lane] + b[lane];
}

// ------------------------------------------------------------------
extern "C" void kernel_launch(void* const* d_in, const int* in_sizes, int n_in,
                              void* d_out, int out_size, void* d_ws, size_t ws_size,
                              hipStream_t stream) {
    const float* x = (const float*)d_in[0];
    const int* esrc = (const int*)d_in[1];
    const int* edst = (const int*)d_in[2];
    const float* W1 = (const float*)d_in[3];
    const float* as1 = (const float*)d_in[4];
    const float* ad1 = (const float*)d_in[5];
    const float* b1 = (const float*)d_in[6];
    const float* W2 = (const float*)d_in[7];
    const float* as2 = (const float*)d_in[8];
    const float* ad2 = (const float*)d_in[9];
    const float* b2 = (const float*)d_in[10];
    // t_Wq/t_Wk/t_bq/t_bk (11,12,14,15) dead: seq_len==1 -> attn = v
    const float* tWv = (const float*)d_in[13];
    const float* tbv = (const float*)d_in[16];
    const float* tWo = (const float*)d_in[17];
    const float* tbo = (const float*)d_in[18];
    const float* tg1 = (const float*)d_in[19];
    const float* tb1 = (const float*)d_in[20];
    const float* tWf1 = (const float*)d_in[21];
    const float* tbf1 = (const float*)d_in[22];
    const float* tWf2 = (const float*)d_in[23];
    const float* tbf2 = (const float*)d_in[24];
    const float* tg2 = (const float*)d_in[25];
    const float* tb2 = (const float*)d_in[26];
    const float* W3 = (const float*)d_in[27];
    const float* as3 = (const float*)d_in[28];
    const float* ad3 = (const float*)d_in[29];
    const float* b3 = (const float*)d_in[30];

    const int n = N_NODES;
    const int E = in_sizes[1];
    const int ET = E + n;

    float* fw = (float*)d_ws;
    float* h1 = fw;                  // [n,256]
    float* agg1 = h1 + 12800000;     // [n,256]
    float* bufA = agg1 + 12800000;   // [n,64]
    float* bufB = bufA + 3200000;
    float* bufC = bufB + 3200000;
    float* bufD = bufC + 3200000;
    float* als = bufD + 3200000;     // [n,4]
    float* ald = als + 200000;
    float* h3 = h1;                  // [n,25], reuses h1 (dead by then)
    int* deg = (int*)(ald + 200000);
    int* rstart = deg + 50016;
    int* cursor = rstart + 50016;
    int* part = cursor + 50016;
    int* csr = part + 64;            // [E+n]

    // weight-split regions live inside dead windows of agg1 / h1:
    //   w1t (2.05 MB) in agg1: written before GEMM1, agg1 rewritten later.
    //   wf  (2 MB) at h1+8M: written after h1's last read, used in loop;
    //   h3 only touches h1[0..1.25M].
    short* w1th = (short*)agg1;              // 512000 shorts
    short* w1tl = w1th + 512000;
    short* wfb = (short*)(h1 + 8000000);
    const size_t WFS = 131072;               // 2048*64
    short* wf1h = wfb;                       // [l][2048][64]
    short* wf1l = wfb + 2 * WFS;
    short* wf2h = wfb + 4 * WFS;             // [l][64][2048]
    short* wf2l = wfb + 6 * WFS;

    float* outAdt = (float*)d_out;                 // [n,25]
    float* outFused = outAdt + (size_t)n * 25;     // [n,64]

    // ---- CSR build ----
    k_zero_i32<<<(150048 + 255) / 256, 256, 0, stream>>>(deg, 150048);
    k_hist<<<(ET + 255) / 256, 256, 0, stream>>>(edst, deg, E, n);
    int nsb = (n + SCAN_B - 1) / SCAN_B;
    k_scan1<<<nsb, SCAN_B, 0, stream>>>(deg, rstart, part, n);
    k_scan2<<<1, 64, 0, stream>>>(part, nsb);
    k_scan3<<<(n + 255) / 256, 256, 0, stream>>>(rstart, part, n);
    k_scatter<<<(ET + 255) / 256, 256, 0, stream>>>(esrc, edst, rstart, cursor, csr, E, n);

    // ---- GAT layer 1 (heads=4, D=64): split-bf16 MFMA GEMM ----
    k_wsplit<<<(512000 + 255) / 256, 256, 0, stream>>>(W1, w1th, w1tl, IN_DIMC, 256);
    k_gemm_sb<<<dim3((n + 127) / 128, 2), 256, 0, stream>>>(x, w1th, w1tl, h1, n, 256, IN_DIMC);
    k_al<4, 64><<<n, 256, 0, stream>>>(h1, as1, ad1, als, ald, n);
    k_gat_agg<4, 64, true><<<n, 256, 0, stream>>>(h1, als, ald, b1, rstart, deg, csr, agg1);

    // FF weight splits (h1 now dead except wf window)
    for (int l = 0; l < 2; l++) {
        k_wsplit<<<(131072 + 255) / 256, 256, 0, stream>>>(tWf1 + (size_t)l * 64 * FF_DIM,
                                                           wf1h + l * WFS, wf1l + l * WFS, 64, FF_DIM);
        k_wsplit<<<(131072 + 255) / 256, 256, 0, stream>>>(tWf2 + (size_t)l * FF_DIM * 64,
                                                           wf2h + l * WFS, wf2l + l * WFS, FF_DIM, 64);
    }

    // ---- GAT layer 2 (heads=1) ----
    k_gemm<128, 64, 16, 1><<<dim3((n + 127) / 128, 1), 256, 0, stream>>>(agg1, W2, nullptr, bufA, n, 64, 256);
    k_al<1, 64><<<(n + 3) / 4, 256, 0, stream>>>(bufA, as2, ad2, als, ald, n);
    k_gat_agg<1, 64, true><<<n, 64, 0, stream>>>(bufA, als, ald, b2, rstart, deg, csr, bufB);

    // ---- Transformer encoder x2 ----
    float* xin = bufB;
    for (int l = 0; l < 2; l++) {
        const float* Wv = tWv + (size_t)l * 64 * 64;
        const float* bv = tbv + (size_t)l * 64;
        const float* Wo = tWo + (size_t)l * 64 * 64;
        const float* bo = tbo + (size_t)l * 64;
        k_gemm<128, 64, 16, 1><<<dim3((n + 127) / 128, 1), 256, 0, stream>>>(xin, Wv, bv, bufC, n, 64, 64);
        k_gemm<128, 64, 16, 1><<<dim3((n + 127) / 128, 1), 256, 0, stream>>>(bufC, Wo, bo, bufD, n, 64, 64);
        k_ln<<<(n + 3) / 4, 256, 0, stream>>>(xin, bufD, tg1 + (size_t)l * 64, tb1 + (size_t)l * 64, bufA, n);
        k_ff_mfma<<<(n + 127) / 128, 256, 0, stream>>>(bufA, wf1h + l * WFS, wf1l + l * WFS,
                                                       tbf1 + (size_t)l * FF_DIM,
                                                       wf2h + l * WFS, wf2l + l * WFS,
                                                       tbf2 + (size_t)l * 64, bufC, n);
        float* xout = (l == 1) ? outFused : bufB;
        k_ln<<<(n + 3) / 4, 256, 0, stream>>>(bufA, bufC, tg2 + (size_t)l * 64, tb2 + (size_t)l * 64, xout, n);
        xin = xout;
    }

    // ---- GAT ADT head (heads=1, D=25) ----
    k_gemm<128, 64, 16, 1><<<dim3((n + 127) / 128, 1), 256, 0, stream>>>(outFused, W3, nullptr, h3, n, 25, 64);
    k_al<1, 25><<<(n + 3) / 4, 256, 0, stream>>>(h3, as3, ad3, als, ald, n);
    k_gat_agg<1, 25, false><<<n, 64, 0, stream>>>(h3, als, ald, b3, rstart, deg, csr, outAdt);
}

// Round 4
// 1483.840 us; speedup vs baseline: 3.1106x; 1.0958x over previous
//
#include <hip/hip_runtime.h>
#include <math.h>

#define N_NODES 50000
#define IN_DIMC 2000
#define FF_DIM 2048
#define EPSV 1e-5f
#define SCAN_B 1024

typedef __attribute__((ext_vector_type(8))) short sh8;
typedef __attribute__((ext_vector_type(4))) short sh4;
typedef __attribute__((ext_vector_type(4))) float f32x4;

// truncation split: f = hi + lo, ~2^-16 rel error
__device__ __forceinline__ void splitf(float f, unsigned short& h, unsigned short& l) {
    unsigned u = __float_as_uint(f);
    h = (unsigned short)(u >> 16);
    float fh = __uint_as_float(u & 0xFFFF0000u);
    l = (unsigned short)(__float_as_uint(f - fh) >> 16);
}

__device__ __forceinline__ void split8(f32x4 a0, f32x4 a1, sh8& hh, sh8& ll) {
    float f[8] = {a0[0], a0[1], a0[2], a0[3], a1[0], a1[1], a1[2], a1[3]};
    sh8 h, l;
#pragma unroll
    for (int j = 0; j < 8; j++) {
        unsigned u = __float_as_uint(f[j]);
        h[j] = (short)(u >> 16);
        float fhi = __uint_as_float(u & 0xFFFF0000u);
        l[j] = (short)(__float_as_uint(f[j] - fhi) >> 16);
    }
    hh = h; ll = l;
}

// async 16B global->LDS; lds dest must be wave-uniform (HW adds lane*16)
__device__ __forceinline__ void gload_lds16(const float* g, float* l) {
    __builtin_amdgcn_global_load_lds(
        (const __attribute__((address_space(1))) unsigned int*)g,
        (__attribute__((address_space(3))) unsigned int*)l, 16, 0, 0);
}

// ------------------------------------------------------------------
// utility / CSR build
// ------------------------------------------------------------------
__global__ void k_zero_i32(int* p, int n) {
    int i = blockIdx.x * blockDim.x + threadIdx.x;
    if (i < n) p[i] = 0;
}

__global__ void k_hist(const int* __restrict__ dst, int* __restrict__ deg, int E, int n) {
    int i = blockIdx.x * blockDim.x + threadIdx.x;
    if (i < E + n) {
        int d = (i < E) ? dst[i] : (i - E);
        atomicAdd(&deg[d], 1);
    }
}

__global__ __launch_bounds__(1024) void k_scan1(const int* __restrict__ deg, int* __restrict__ rstart,
                                                int* __restrict__ part, int n) {
    __shared__ int lds[SCAN_B];
    int t = threadIdx.x;
    int base = blockIdx.x * SCAN_B;
    int v = (base + t < n) ? deg[base + t] : 0;
    lds[t] = v;
    __syncthreads();
    for (int o = 1; o < SCAN_B; o <<= 1) {
        int add = (t >= o) ? lds[t - o] : 0;
        __syncthreads();
        lds[t] += add;
        __syncthreads();
    }
    if (base + t < n) rstart[base + t] = lds[t] - v;
    if (t == SCAN_B - 1) part[blockIdx.x] = lds[t];
}

__global__ void k_scan2(int* part, int nb) {
    if (threadIdx.x == 0 && blockIdx.x == 0) {
        int s = 0;
        for (int i = 0; i < nb; i++) { int v = part[i]; part[i] = s; s += v; }
    }
}

__global__ void k_scan3(int* rstart, const int* __restrict__ part, int n) {
    int i = blockIdx.x * blockDim.x + threadIdx.x;
    if (i < n) rstart[i] += part[i / SCAN_B];
}

__global__ void k_scatter(const int* __restrict__ src, const int* __restrict__ dst,
                          const int* __restrict__ rstart, int* __restrict__ cursor,
                          int* __restrict__ csr_src, int E, int n) {
    int i = blockIdx.x * blockDim.x + threadIdx.x;
    if (i < E + n) {
        int s, d;
        if (i < E) { s = src[i]; d = dst[i]; } else { s = i - E; d = s; }
        int pos = rstart[d] + atomicAdd(&cursor[d], 1);
        csr_src[pos] = s;
    }
}

// ------------------------------------------------------------------
// weight pre-split with zero padding: W [K][N] -> Wt hi/lo [Npad][Kpad]
// (zero pads make the GEMM's ragged-K clamp trick exact: A-garbage * 0)
// ------------------------------------------------------------------
__global__ void k_wsplit_pad(const float* __restrict__ W, short* __restrict__ oh,
                             short* __restrict__ ol, int K, int N, int Kpad, int Npad) {
    int i = blockIdx.x * blockDim.x + threadIdx.x;
    if (i < Kpad * Npad) {
        int c = i / Kpad, k = i - c * Kpad;
        float v = (c < N && k < K) ? W[(size_t)k * N + c] : 0.f;
        unsigned short h, l;
        splitf(v, h, l);
        oh[i] = (short)h; ol[i] = (short)l;
    }
}

// non-padded transposing split (FF weights, exact sizes)
__global__ void k_wsplit(const float* __restrict__ W, short* __restrict__ oh,
                         short* __restrict__ ol, int K, int N) {
    int i = blockIdx.x * blockDim.x + threadIdx.x;
    if (i < K * N) {
        int k = i / N, c = i - k * N;
        unsigned short h, l;
        splitf(W[i], h, l);
        oh[(size_t)c * K + k] = (short)h;
        ol[(size_t)c * K + k] = (short)l;
    }
}

// combined attn weights: Wc = Wv@Wo (split+transposed), bc = bv@Wo + bo
__global__ void k_wcomb(const float* __restrict__ Wv, const float* __restrict__ bv,
                        const float* __restrict__ Wo, const float* __restrict__ bo,
                        short* __restrict__ och, short* __restrict__ ocl, float* __restrict__ bc) {
    int i = blockIdx.x * blockDim.x + threadIdx.x;
    if (i < 4096) {
        int cc = i & 63, kk = i >> 6;
        float s = 0.f;
        for (int j = 0; j < 64; j++) s += Wv[kk * 64 + j] * Wo[j * 64 + cc];
        unsigned short h, l;
        splitf(s, h, l);
        och[cc * 64 + kk] = (short)h;
        ocl[cc * 64 + kk] = (short)l;
        if (kk == 0) {
            float t = bo[cc];
            for (int j = 0; j < 64; j++) t += bv[j] * Wo[j * 64 + cc];
            bc[cc] = t;
        }
    }
}

// ------------------------------------------------------------------
// split-bf16 MFMA GEMM v2: C[M,N] = A[M,K] @ B[K,N] (+bias)
// A fp32 staged RAW via async global_load_lds into XOR-swizzled LDS
// (pre-swizzled per-lane source, linear dest, swizzled read); hi/lo
// split happens at fragment read (VALU overlaps MFMA pipe, m114).
// B pre-split bf16 [Npad][Kpad], zero-padded. 128 x (NF*32) tile, BK=64.
// LDS: A 32K + B 2*NF*4K -> NF=4: 64KB (2 blk/CU), NF=2: 48KB (3 blk/CU).
// ------------------------------------------------------------------
template<int NF>
__global__ __launch_bounds__(256, 2) void k_gemm_x(const float* __restrict__ A,
                                                   const short* __restrict__ Bth,
                                                   const short* __restrict__ Btl,
                                                   const float* __restrict__ bias,
                                                   float* __restrict__ C,
                                                   int M, int N, int K, int Kpad) {
    constexpr int BN = NF * 32;
    __shared__ float Afs[128 * 64];
    __shared__ short Bhs[BN * 64];
    __shared__ short Bls[BN * 64];
    int tid = threadIdx.x;
    int wave = tid >> 6, lane = tid & 63;
    int wm = wave & 1, wn = wave >> 1;
    int l15 = lane & 15, l4 = lane >> 4;
    long m0 = (long)blockIdx.x * 128;
    int n0 = blockIdx.y * BN;
    int chunks = K >> 2;               // 16B chunks per A row (K % 4 == 0)
    int cmax = chunks - 1;
    int ktiles = (chunks + 15) >> 4;
    f32x4 acc[4][NF] = {};
    int Sl = wave * 512 + lane;        // A slot id for this lane, instr 0
    for (int kt = 0; kt < ktiles; kt++) {
        int c0 = kt << 4;
        // A: 8 async direct-to-LDS 16B loads per wave.
        // LDS[row][slot] holds global chunk (c0 + (slot^ (row&7))); the frag
        // read applies the same XOR, so content aligns; clamp handles K tail
        // (duplicated data * zero-padded B = 0).
#pragma unroll
        for (int i = 0; i < 8; i++) {
            int S = Sl + i * 64;
            int row = S >> 4, slot = S & 15;
            long srcrow = m0 + row; if (srcrow > (long)M - 1) srcrow = M - 1;
            int ch = c0 + (slot ^ (row & 7)); if (ch > cmax) ch = cmax;
            gload_lds16(A + (size_t)srcrow * K + (size_t)ch * 4,
                        &Afs[(wave * 512 + i * 64) * 4]);
        }
        // B: regs -> swizzled LDS (L2-hot, zero-padded so no guards)
#pragma unroll
        for (int p = 0; p < NF; p++) {
            int u = tid + p * 256;
            int col = u >> 3, k8 = u & 7;
            size_t src = (size_t)(n0 + col) * Kpad + (size_t)kt * 64 + k8 * 8;
            sh8 bh = *(const sh8*)&Bth[src];
            sh8 bl = *(const sh8*)&Btl[src];
            int doff = col * 64 + ((k8 ^ (col & 7)) << 3);
            *(sh8*)&Bhs[doff] = bh;
            *(sh8*)&Bls[doff] = bl;
        }
        __syncthreads();
#pragma unroll
        for (int kf = 0; kf < 2; kf++) {
            sh8 ah[4], al[4];
#pragma unroll
            for (int mf = 0; mf < 4; mf++) {
                int row = wm * 64 + mf * 16 + l15;
                int s0 = kf * 8 + l4 * 2;
                f32x4 a0 = *(const f32x4*)&Afs[row * 64 + ((s0 ^ (row & 7)) << 2)];
                f32x4 a1 = *(const f32x4*)&Afs[row * 64 + (((s0 + 1) ^ (row & 7)) << 2)];
                split8(a0, a1, ah[mf], al[mf]);
            }
#pragma unroll
            for (int nf = 0; nf < NF; nf++) {
                int col = wn * (NF * 16) + nf * 16 + l15;
                int k8 = kf * 4 + l4;
                int boff = col * 64 + ((k8 ^ (col & 7)) << 3);
                sh8 bh = *(const sh8*)&Bhs[boff];
                sh8 bl = *(const sh8*)&Bls[boff];
#pragma unroll
                for (int mf = 0; mf < 4; mf++) {
                    f32x4 c = acc[mf][nf];
                    c = __builtin_amdgcn_mfma_f32_16x16x32_bf16(ah[mf], bh, c, 0, 0, 0);
                    c = __builtin_amdgcn_mfma_f32_16x16x32_bf16(ah[mf], bl, c, 0, 0, 0);
                    c = __builtin_amdgcn_mfma_f32_16x16x32_bf16(al[mf], bh, c, 0, 0, 0);
                    acc[mf][nf] = c;
                }
            }
        }
        __syncthreads();
    }
#pragma unroll
    for (int mf = 0; mf < 4; mf++)
#pragma unroll
        for (int r = 0; r < 4; r++) {
            long gm = m0 + wm * 64 + mf * 16 + l4 * 4 + r;
            if (gm >= M) continue;
#pragma unroll
            for (int nf = 0; nf < NF; nf++) {
                int gc = n0 + wn * (NF * 16) + nf * 16 + l15;
                if (gc < N) C[gm * (size_t)N + gc] = acc[mf][nf][r] + (bias ? bias[gc] : 0.f);
            }
        }
}

// ------------------------------------------------------------------
// fused FF with split-bf16 MFMA (unchanged from R3; verified pass)
// ------------------------------------------------------------------
__global__ __launch_bounds__(256, 2) void k_ff_mfma(const float* __restrict__ x,
                                                    const short* __restrict__ W1h, const short* __restrict__ W1l,
                                                    const float* __restrict__ bf1,
                                                    const short* __restrict__ W2h, const short* __restrict__ W2l,
                                                    const float* __restrict__ bf2,
                                                    float* __restrict__ out, int n) {
    __shared__ short lds[36864];
    short* Hh = lds;
    short* Hl = lds + 9216;
    short* w1h = lds + 18432;
    short* w1l = lds + 23040;
    short* w2h = lds + 27648;
    short* w2l = lds + 32256;
    int tid = threadIdx.x;
    int wave = tid >> 6, lane = tid & 63;
    int wm = wave & 1, wn = wave >> 1;
    int l15 = lane & 15, l4 = lane >> 4;
    long row0 = (long)blockIdx.x * 128;
#pragma unroll
    for (int p = 0; p < 8; p++) {
        int f4 = tid + p * 256;
        int row = f4 >> 4, kq = f4 & 15;
        long gr = row0 + row;
        float4 a = {0.f, 0.f, 0.f, 0.f};
        if (gr < n) a = *(const float4*)&x[gr * 64 + kq * 4];
        unsigned short h0, h1, h2, h3, l0, l1, l2, l3;
        splitf(a.x, h0, l0); splitf(a.y, h1, l1);
        splitf(a.z, h2, l2); splitf(a.w, h3, l3);
        sh4 hv = {(short)h0, (short)h1, (short)h2, (short)h3};
        sh4 lv = {(short)l0, (short)l1, (short)l2, (short)l3};
        *(sh4*)&Hh[row * 72 + kq * 4] = hv;
        *(sh4*)&Hl[row * 72 + kq * 4] = lv;
    }
    __syncthreads();
    sh8 xh[4][2], xl[4][2];
#pragma unroll
    for (int mf = 0; mf < 4; mf++)
#pragma unroll
        for (int kf = 0; kf < 2; kf++) {
            int off = (wm * 64 + mf * 16 + l15) * 72 + kf * 32 + l4 * 8;
            xh[mf][kf] = *(const sh8*)&Hh[off];
            xl[mf][kf] = *(const sh8*)&Hl[off];
        }
    f32x4 acc2[4][2] = {};
    for (int j0 = 0; j0 < FF_DIM; j0 += 64) {
#pragma unroll
        for (int p = 0; p < 2; p++) {
            int u = tid + p * 256;
            int cj = u >> 3, kq8 = u & 7;
            *(sh8*)&w1h[cj * 72 + kq8 * 8] = *(const sh8*)&W1h[(size_t)(j0 + cj) * 64 + kq8 * 8];
            *(sh8*)&w1l[cj * 72 + kq8 * 8] = *(const sh8*)&W1l[(size_t)(j0 + cj) * 64 + kq8 * 8];
            *(sh8*)&w2h[cj * 72 + kq8 * 8] = *(const sh8*)&W2h[(size_t)cj * FF_DIM + j0 + kq8 * 8];
            *(sh8*)&w2l[cj * 72 + kq8 * 8] = *(const sh8*)&W2l[(size_t)cj * FF_DIM + j0 + kq8 * 8];
        }
        __syncthreads();
        f32x4 hacc[4][2] = {};
#pragma unroll
        for (int kf = 0; kf < 2; kf++) {
            sh8 bh[2], bl[2];
#pragma unroll
            for (int nf = 0; nf < 2; nf++) {
                int off = (wn * 32 + nf * 16 + l15) * 72 + kf * 32 + l4 * 8;
                bh[nf] = *(const sh8*)&w1h[off];
                bl[nf] = *(const sh8*)&w1l[off];
            }
#pragma unroll
            for (int mf = 0; mf < 4; mf++)
#pragma unroll
                for (int nf = 0; nf < 2; nf++) {
                    f32x4 c = hacc[mf][nf];
                    c = __builtin_amdgcn_mfma_f32_16x16x32_bf16(xh[mf][kf], bh[nf], c, 0, 0, 0);
                    c = __builtin_amdgcn_mfma_f32_16x16x32_bf16(xh[mf][kf], bl[nf], c, 0, 0, 0);
                    c = __builtin_amdgcn_mfma_f32_16x16x32_bf16(xl[mf][kf], bh[nf], c, 0, 0, 0);
                    hacc[mf][nf] = c;
                }
        }
#pragma unroll
        for (int mf = 0; mf < 4; mf++)
#pragma unroll
            for (int nf = 0; nf < 2; nf++) {
                int col = wn * 32 + nf * 16 + l15;
                float b1v = bf1[j0 + col];
#pragma unroll
                for (int r = 0; r < 4; r++) {
                    int row = wm * 64 + mf * 16 + l4 * 4 + r;
                    float v = fmaxf(hacc[mf][nf][r] + b1v, 0.f);
                    unsigned short h, l;
                    splitf(v, h, l);
                    Hh[row * 72 + col] = (short)h;
                    Hl[row * 72 + col] = (short)l;
                }
            }
        __syncthreads();
#pragma unroll
        for (int kf = 0; kf < 2; kf++) {
            sh8 ah[4], alv[4], bh[2], bl[2];
#pragma unroll
            for (int mf = 0; mf < 4; mf++) {
                int off = (wm * 64 + mf * 16 + l15) * 72 + kf * 32 + l4 * 8;
                ah[mf] = *(const sh8*)&Hh[off];
                alv[mf] = *(const sh8*)&Hl[off];
            }
#pragma unroll
            for (int nf = 0; nf < 2; nf++) {
                int off = (wn * 32 + nf * 16 + l15) * 72 + kf * 32 + l4 * 8;
                bh[nf] = *(const sh8*)&w2h[off];
                bl[nf] = *(const sh8*)&w2l[off];
            }
#pragma unroll
            for (int mf = 0; mf < 4; mf++)
#pragma unroll
                for (int nf = 0; nf < 2; nf++) {
                    f32x4 c = acc2[mf][nf];
                    c = __builtin_amdgcn_mfma_f32_16x16x32_bf16(ah[mf], bh[nf], c, 0, 0, 0);
                    c = __builtin_amdgcn_mfma_f32_16x16x32_bf16(ah[mf], bl[nf], c, 0, 0, 0);
                    c = __builtin_amdgcn_mfma_f32_16x16x32_bf16(alv[mf], bh[nf], c, 0, 0, 0);
                    acc2[mf][nf] = c;
                }
        }
        __syncthreads();
    }
#pragma unroll
    for (int mf = 0; mf < 4; mf++)
#pragma unroll
        for (int r = 0; r < 4; r++) {
            long gr = row0 + wm * 64 + mf * 16 + l4 * 4 + r;
            if (gr >= n) continue;
#pragma unroll
            for (int nf = 0; nf < 2; nf++) {
                int gc = wn * 32 + nf * 16 + l15;
                out[gr * 64 + gc] = acc2[mf][nf][r] + bf2[gc];
            }
        }
}

// ------------------------------------------------------------------
// per-(node,head) attention logits
// ------------------------------------------------------------------
template<int H, int D>
__global__ void k_al(const float* __restrict__ h, const float* __restrict__ a_src,
                     const float* __restrict__ a_dst, float* __restrict__ als,
                     float* __restrict__ ald, int n) {
    long w = ((long)blockIdx.x * blockDim.x + threadIdx.x) >> 6;
    int lane = threadIdx.x & 63;
    long nn = w / H;
    int hh = (int)(w % H);
    if (nn >= n) return;
    float v = 0.f, u = 0.f;
    if (lane < D) {
        float hv = h[nn * (H * D) + hh * D + lane];
        v = hv * a_src[hh * D + lane];
        u = hv * a_dst[hh * D + lane];
    }
#pragma unroll
    for (int o = 32; o > 0; o >>= 1) {
        v += __shfl_xor(v, o, 64);
        u += __shfl_xor(u, o, 64);
    }
    if (lane == 0) { als[nn * H + hh] = v; ald[nn * H + hh] = u; }
}

// ------------------------------------------------------------------
// GAT segment-softmax + aggregation: one WAVE per node (no barriers,
// no LDS; 4 nodes/block; shfl-broadcast per-head weights)
// ------------------------------------------------------------------
template<int H, int D, bool DO_ELU>
__global__ __launch_bounds__(256) void k_gat_agg_w(const float* __restrict__ h,
                                                   const float* __restrict__ als,
                                                   const float* __restrict__ ald,
                                                   const float* __restrict__ bias,
                                                   const int* __restrict__ rstart,
                                                   const int* __restrict__ deg,
                                                   const int* __restrict__ csr_src,
                                                   float* __restrict__ out, int n) {
    int wid = (int)(((long)blockIdx.x * blockDim.x + threadIdx.x) >> 6);
    int lane = threadIdx.x & 63;
    if (wid >= n) return;
    int beg = rstart[wid], cnt = deg[wid];
    float aldv = 0.f;
    if (lane < H) aldv = ald[wid * H + lane];
    float wsum = 0.f;
    float acc[H];
#pragma unroll
    for (int i = 0; i < H; i++) acc[i] = 0.f;
    for (int e = 0; e < cnt; e++) {
        int s = csr_src[beg + e];
        float w = 0.f;
        if (lane < H) {
            float lg = als[s * H + lane] + aldv;
            lg = (lg > 0.f) ? lg : 0.2f * lg;
            w = __expf(lg);
            wsum += w;
        }
#pragma unroll
        for (int hh = 0; hh < H; hh++) {
            float wv = __shfl(w, hh, 64);
            float hv = (lane < D) ? h[(size_t)s * (H * D) + hh * D + lane] : 0.f;
            acc[hh] += wv * hv;
        }
    }
#pragma unroll
    for (int hh = 0; hh < H; hh++) {
        float ws = __shfl(wsum, hh, 64);
        if (lane < D) {
            float v = acc[hh] / (ws + 1e-16f) + bias[hh * D + lane];
            if (DO_ELU) v = (v > 0.f) ? v : expm1f(v);
            out[(size_t)wid * (H * D) + hh * D + lane] = v;
        }
    }
}

// ------------------------------------------------------------------
// residual + LayerNorm (64-dim rows, wave per row)
// ------------------------------------------------------------------
__global__ void k_ln(const float* __restrict__ x, const float* __restrict__ y,
                     const float* __restrict__ g, const float* __restrict__ b,
                     float* __restrict__ out, int n) {
    long w = ((long)blockIdx.x * blockDim.x + threadIdx.x) >> 6;
    int lane = threadIdx.x & 63;
    if (w >= n) return;
    float v = x[w * 64 + lane] + y[w * 64 + lane];
    float s = v;
#pragma unroll
    for (int o = 32; o > 0; o >>= 1) s += __shfl_xor(s, o, 64);
    float mu = s * (1.f / 64.f);
    float dv = v - mu;
    float q = dv * dv;
#pragma unroll
    for (int o = 32; o > 0; o >>= 1) q += __shfl_xor(q, o, 64);
    float var = q * (1.f / 64.f);
    out[w * 64 + lane] = dv * rsqrtf(var + EPSV) * g[lane] + b[lane];
}

// ------------------------------------------------------------------
extern "C" void kernel_launch(void* const* d_in, const int* in_sizes, int n_in,
                              void* d_out, int out_size, void* d_ws, size_t ws_size,
                              hipStream_t stream) {
    const float* x = (const float*)d_in[0];
    const int* esrc = (const int*)d_in[1];
    const int* edst = (const int*)d_in[2];
    const float* W1 = (const float*)d_in[3];
    const float* as1 = (const float*)d_in[4];
    const float* ad1 = (const float*)d_in[5];
    const float* b1 = (const float*)d_in[6];
    const float* W2 = (const float*)d_in[7];
    const float* as2 = (const float*)d_in[8];
    const float* ad2 = (const float*)d_in[9];
    const float* b2 = (const float*)d_in[10];
    // t_Wq/t_Wk/t_bq/t_bk (11,12,14,15) dead: seq_len==1 -> attn = v
    const float* tWv = (const float*)d_in[13];
    const float* tbv = (const float*)d_in[16];
    const float* tWo = (const float*)d_in[17];
    const float* tbo = (const float*)d_in[18];
    const float* tg1 = (const float*)d_in[19];
    const float* tb1 = (const float*)d_in[20];
    const float* tWf1 = (const float*)d_in[21];
    const float* tbf1 = (const float*)d_in[22];
    const float* tWf2 = (const float*)d_in[23];
    const float* tbf2 = (const float*)d_in[24];
    const float* tg2 = (const float*)d_in[25];
    const float* tb2 = (const float*)d_in[26];
    const float* W3 = (const float*)d_in[27];
    const float* as3 = (const float*)d_in[28];
    const float* ad3 = (const float*)d_in[29];
    const float* b3 = (const float*)d_in[30];

    const int n = N_NODES;
    const int E = in_sizes[1];
    const int ET = E + n;

    // ---- workspace layout (no overlays), ~163 MB ----
    float* fw = (float*)d_ws;
    float* h1 = fw;                        // [n,256]
    float* agg1 = fw + 12800000;           // [n,256]
    float* bufA = fw + 25600000;           // [n,64]
    float* bufB = fw + 28800000;
    float* bufC = fw + 32000000;
    float* bufD = fw + 35200000;
    float* als = fw + 38400000;            // [n,4]
    float* ald = fw + 38600000;
    float* bc = fw + 38800000;             // [64]
    int* deg = (int*)(fw + 38800064);
    int* rstart = deg + 50016;
    int* cursor = rstart + 50016;
    int* part = cursor + 50016;
    int* csr = part + 64;                  // [E+n] <= 700000
    short* sbase = (short*)(csr + 700000);
    short* w1th = sbase;                   // [256][2048]
    short* w1tl = w1th + 524288;
    short* w2th = w1tl + 524288;           // [64][256]
    short* w2tl = w2th + 16384;
    short* w3th = w2tl + 16384;            // [64][64] (cols 25..63 zero)
    short* w3tl = w3th + 4096;
    short* wcth = w3tl + 4096;             // [64][64] combined attn
    short* wctl = wcth + 4096;
    const size_t WFS = 131072;             // 2048*64
    short* wf1h = wctl + 4096;             // [l][2048][64]
    short* wf1l = wf1h + 2 * WFS;
    short* wf2h = wf1l + 2 * WFS;          // [l][64][2048]
    short* wf2l = wf2h + 2 * WFS;
    float* h3 = h1;                        // [n,25] reuses h1 (dead by then)

    float* outAdt = (float*)d_out;                 // [n,25]
    float* outFused = outAdt + (size_t)n * 25;     // [n,64]

    // ---- CSR build ----
    k_zero_i32<<<(150048 + 255) / 256, 256, 0, stream>>>(deg, 150048);
    k_hist<<<(ET + 255) / 256, 256, 0, stream>>>(edst, deg, E, n);
    int nsb = (n + SCAN_B - 1) / SCAN_B;
    k_scan1<<<nsb, SCAN_B, 0, stream>>>(deg, rstart, part, n);
    k_scan2<<<1, 64, 0, stream>>>(part, nsb);
    k_scan3<<<(n + 255) / 256, 256, 0, stream>>>(rstart, part, n);
    k_scatter<<<(ET + 255) / 256, 256, 0, stream>>>(esrc, edst, rstart, cursor, csr, E, n);

    // ---- weight preprocessing ----
    k_wsplit_pad<<<(524288 + 255) / 256, 256, 0, stream>>>(W1, w1th, w1tl, IN_DIMC, 256, 2048, 256);
    k_wsplit_pad<<<(16384 + 255) / 256, 256, 0, stream>>>(W2, w2th, w2tl, 256, 64, 256, 64);
    k_wsplit_pad<<<(4096 + 255) / 256, 256, 0, stream>>>(W3, w3th, w3tl, 64, 25, 64, 64);
    for (int l = 0; l < 2; l++) {
        k_wsplit<<<(131072 + 255) / 256, 256, 0, stream>>>(tWf1 + (size_t)l * 64 * FF_DIM,
                                                           wf1h + l * WFS, wf1l + l * WFS, 64, FF_DIM);
        k_wsplit<<<(131072 + 255) / 256, 256, 0, stream>>>(tWf2 + (size_t)l * FF_DIM * 64,
                                                           wf2h + l * WFS, wf2l + l * WFS, FF_DIM, 64);
    }

    // ---- GAT layer 1 (heads=4, D=64) ----
    k_gemm_x<4><<<dim3((n + 127) / 128, 2), 256, 0, stream>>>(x, w1th, w1tl, nullptr, h1, n, 256, IN_DIMC, 2048);
    k_al<4, 64><<<n, 256, 0, stream>>>(h1, as1, ad1, als, ald, n);
    k_gat_agg_w<4, 64, true><<<(n + 3) / 4, 256, 0, stream>>>(h1, als, ald, b1, rstart, deg, csr, agg1, n);

    // ---- GAT layer 2 (heads=1, D=64) ----
    k_gemm_x<2><<<dim3((n + 127) / 128, 1), 256, 0, stream>>>(agg1, w2th, w2tl, nullptr, bufA, n, 64, 256, 256);
    k_al<1, 64><<<(n + 3) / 4, 256, 0, stream>>>(bufA, as2, ad2, als, ald, n);
    k_gat_agg_w<1, 64, true><<<(n + 3) / 4, 256, 0, stream>>>(bufA, als, ald, b2, rstart, deg, csr, bufB, n);

    // ---- Transformer encoder x2 (attn = x@(Wv@Wo) + (bv@Wo+bo)) ----
    float* xin = bufB;
    for (int l = 0; l < 2; l++) {
        k_wcomb<<<16, 256, 0, stream>>>(tWv + (size_t)l * 4096, tbv + (size_t)l * 64,
                                        tWo + (size_t)l * 4096, tbo + (size_t)l * 64,
                                        wcth, wctl, bc);
        k_gemm_x<2><<<dim3((n + 127) / 128, 1), 256, 0, stream>>>(xin, wcth, wctl, bc, bufD, n, 64, 64, 64);
        k_ln<<<(n + 3) / 4, 256, 0, stream>>>(xin, bufD, tg1 + (size_t)l * 64, tb1 + (size_t)l * 64, bufA, n);
        k_ff_mfma<<<(n + 127) / 128, 256, 0, stream>>>(bufA, wf1h + l * WFS, wf1l + l * WFS,
                                                       tbf1 + (size_t)l * FF_DIM,
                                                       wf2h + l * WFS, wf2l + l * WFS,
                                                       tbf2 + (size_t)l * 64, bufC, n);
        float* xout = (l == 1) ? outFused : bufB;
        k_ln<<<(n + 3) / 4, 256, 0, stream>>>(bufA, bufC, tg2 + (size_t)l * 64, tb2 + (size_t)l * 64, xout, n);
        xin = xout;
    }

    // ---- GAT ADT head (heads=1, D=25, no ELU) ----
    k_gemm_x<2><<<dim3((n + 127) / 128, 1), 256, 0, stream>>>(outFused, w3th, w3tl, nullptr, h3, n, 25, 64, 64);
    k_al<1, 25><<<(n + 3) / 4, 256, 0, stream>>>(h3, as3, ad3, als, ald, n);
    k_gat_agg_w<1, 25, false><<<(n + 3) / 4, 256, 0, stream>>>(h3, als, ald, b3, rstart, deg, csr, outAdt, n);
}

// Round 7
// 1394.007 us; speedup vs baseline: 3.3110x; 1.0644x over previous
//
#include <hip/hip_runtime.h>
#include <math.h>

#define N_NODES 50000
#define IN_DIMC 2000
#define FF_DIM 2048
#define EPSV 1e-5f
#define SCAN_B 1024

typedef __attribute__((ext_vector_type(8))) short sh8;
typedef __attribute__((ext_vector_type(4))) short sh4;
typedef __attribute__((ext_vector_type(4))) float f32x4;

// truncation split: f = hi + lo, ~2^-16 rel error
__device__ __forceinline__ void splitf(float f, unsigned short& h, unsigned short& l) {
    unsigned u = __float_as_uint(f);
    h = (unsigned short)(u >> 16);
    float fh = __uint_as_float(u & 0xFFFF0000u);
    l = (unsigned short)(__float_as_uint(f - fh) >> 16);
}

__device__ __forceinline__ void split8(f32x4 a0, f32x4 a1, sh8& hh, sh8& ll) {
    float f[8] = {a0[0], a0[1], a0[2], a0[3], a1[0], a1[1], a1[2], a1[3]};
    sh8 h, l;
#pragma unroll
    for (int j = 0; j < 8; j++) {
        unsigned u = __float_as_uint(f[j]);
        h[j] = (short)(u >> 16);
        float fhi = __uint_as_float(u & 0xFFFF0000u);
        l[j] = (short)(__float_as_uint(f[j] - fhi) >> 16);
    }
    hh = h; ll = l;
}

// async 16B global->LDS; lds dest wave-uniform (HW adds lane*16)
__device__ __forceinline__ void gload_lds16(const void* g, void* l) {
    __builtin_amdgcn_global_load_lds(
        (const __attribute__((address_space(1))) unsigned int*)g,
        (__attribute__((address_space(3))) unsigned int*)l, 16, 0, 0);
}

// ------------------------------------------------------------------
// utility / CSR build
// ------------------------------------------------------------------
__global__ void k_zero_i32(int* p, int n) {
    int i = blockIdx.x * blockDim.x + threadIdx.x;
    if (i < n) p[i] = 0;
}

__global__ void k_hist(const int* __restrict__ dst, int* __restrict__ deg, int E, int n) {
    int i = blockIdx.x * blockDim.x + threadIdx.x;
    if (i < E + n) {
        int d = (i < E) ? dst[i] : (i - E);
        atomicAdd(&deg[d], 1);
    }
}

__global__ __launch_bounds__(1024) void k_scan1(const int* __restrict__ deg, int* __restrict__ rstart,
                                                int* __restrict__ part, int n) {
    __shared__ int lds[SCAN_B];
    int t = threadIdx.x;
    int base = blockIdx.x * SCAN_B;
    int v = (base + t < n) ? deg[base + t] : 0;
    lds[t] = v;
    __syncthreads();
    for (int o = 1; o < SCAN_B; o <<= 1) {
        int add = (t >= o) ? lds[t - o] : 0;
        __syncthreads();
        lds[t] += add;
        __syncthreads();
    }
    if (base + t < n) rstart[base + t] = lds[t] - v;
    if (t == SCAN_B - 1) part[blockIdx.x] = lds[t];
}

__global__ void k_scan2(int* part, int nb) {
    if (threadIdx.x == 0 && blockIdx.x == 0) {
        int s = 0;
        for (int i = 0; i < nb; i++) { int v = part[i]; part[i] = s; s += v; }
    }
}

__global__ void k_scan3(int* rstart, const int* __restrict__ part, int n) {
    int i = blockIdx.x * blockDim.x + threadIdx.x;
    if (i < n) rstart[i] += part[i / SCAN_B];
}

__global__ void k_scatter(const int* __restrict__ src, const int* __restrict__ dst,
                          const int* __restrict__ rstart, int* __restrict__ cursor,
                          int* __restrict__ csr_src, int E, int n) {
    int i = blockIdx.x * blockDim.x + threadIdx.x;
    if (i < E + n) {
        int s, d;
        if (i < E) { s = src[i]; d = dst[i]; } else { s = i - E; d = s; }
        int pos = rstart[d] + atomicAdd(&cursor[d], 1);
        csr_src[pos] = s;
    }
}

// ------------------------------------------------------------------
// weight pre-split with zero padding: W [K][N] -> Wt hi/lo [Npad][Kpad]
// ------------------------------------------------------------------
__global__ void k_wsplit_pad(const float* __restrict__ W, short* __restrict__ oh,
                             short* __restrict__ ol, int K, int N, int Kpad, int Npad) {
    int i = blockIdx.x * blockDim.x + threadIdx.x;
    if (i < Kpad * Npad) {
        int c = i / Kpad, k = i - c * Kpad;
        float v = (c < N && k < K) ? W[(size_t)k * N + c] : 0.f;
        unsigned short h, l;
        splitf(v, h, l);
        oh[i] = (short)h; ol[i] = (short)l;
    }
}

// non-padded transposing split (FF weights, exact sizes)
__global__ void k_wsplit(const float* __restrict__ W, short* __restrict__ oh,
                         short* __restrict__ ol, int K, int N) {
    int i = blockIdx.x * blockDim.x + threadIdx.x;
    if (i < K * N) {
        int k = i / N, c = i - k * N;
        unsigned short h, l;
        splitf(W[i], h, l);
        oh[(size_t)c * K + k] = (short)h;
        ol[(size_t)c * K + k] = (short)l;
    }
}

// combined attn weights: Wc = Wv@Wo (split+transposed), bc = bv@Wo + bo
__global__ void k_wcomb(const float* __restrict__ Wv, const float* __restrict__ bv,
                        const float* __restrict__ Wo, const float* __restrict__ bo,
                        short* __restrict__ och, short* __restrict__ ocl, float* __restrict__ bc) {
    int i = blockIdx.x * blockDim.x + threadIdx.x;
    if (i < 4096) {
        int cc = i & 63, kk = i >> 6;
        float s = 0.f;
        for (int j = 0; j < 64; j++) s += Wv[kk * 64 + j] * Wo[j * 64 + cc];
        unsigned short h, l;
        splitf(s, h, l);
        och[cc * 64 + kk] = (short)h;
        ocl[cc * 64 + kk] = (short)l;
        if (kk == 0) {
            float t = bo[cc];
            for (int j = 0; j < 64; j++) t += bv[j] * Wo[j * 64 + cc];
            bc[cc] = t;
        }
    }
}

// ------------------------------------------------------------------
// split-bf16 MFMA GEMM v3: 2-phase pipelined (T3-minimal), BK=32,
// double-buffered A (raw fp32) and B (bf16 hi/lo) both staged via
// async global_load_lds with pre-swizzled per-lane sources.
// Prefetch tile t+1 issued BEFORE compute of tile t; ONE barrier/tile.
// A LDS row = 32 floats, 8 slots of 16B; slot s holds chunk s^(row&7).
// B LDS row (per col) = 64 shorts, 8 slots; slot s holds c=s^(col&7):
//   c<4 -> hi k-group c, c>=4 -> lo k-group c-4.
// LDS: NF=4: 2*16K(A) + 2*16K(B) = 64KB (2 blk/CU); NF=2: 48KB.
// ------------------------------------------------------------------
template<int NF>
__global__ __launch_bounds__(256, 2) void k_gemm_p(const float* __restrict__ A,
                                                   const short* __restrict__ Bth,
                                                   const short* __restrict__ Btl,
                                                   const float* __restrict__ bias,
                                                   float* __restrict__ C,
                                                   int M, int N, int K, int Kpad) {
    constexpr int BN = NF * 32;
    constexpr int NB = BN / 32;            // B stage instrs per wave
    __shared__ float Afs[2][128 * 32];
    __shared__ short Bs[2][BN * 64];
    int tid = threadIdx.x;
    int wave = tid >> 6, lane = tid & 63;
    int wm = wave & 1, wn = wave >> 1;
    int l15 = lane & 15, l4 = lane >> 4;
    long m0 = (long)blockIdx.x * 128;
    int n0 = blockIdx.y * BN;
    int cmax = (K >> 2) - 1;               // last 16B chunk (K % 4 == 0)
    int ktiles = (K + 31) >> 5;
    f32x4 acc[4][NF] = {};

    auto stage = [&](int kt, int b) {
        int c0 = kt << 3;
        // A: 4 instrs/wave, 64 slots each
#pragma unroll
        for (int i = 0; i < 4; i++) {
            int S = (wave * 4 + i) * 64 + lane;
            int row = S >> 3, slot = S & 7;
            long srcrow = m0 + row; if (srcrow > (long)M - 1) srcrow = M - 1;
            int ch = c0 + (slot ^ (row & 7)); if (ch > cmax) ch = cmax;
            gload_lds16(A + (size_t)srcrow * K + (size_t)ch * 4,
                        &Afs[b][(wave * 4 + i) * 256]);
        }
        // B: NB instrs/wave; hi/lo interleaved via content chunk c
#pragma unroll
        for (int i = 0; i < NB; i++) {
            int S = (wave * NB + i) * 64 + lane;
            int col = S >> 3, slot = S & 7;
            int c = slot ^ (col & 7);
            const short* src = (c < 4)
                ? Bth + (size_t)(n0 + col) * Kpad + kt * 32 + c * 8
                : Btl + (size_t)(n0 + col) * Kpad + kt * 32 + (c - 4) * 8;
            gload_lds16(src, &Bs[b][(wave * NB + i) * 512]);
        }
    };

    stage(0, 0);
    __syncthreads();
    int b = 0;
    for (int kt = 0; kt < ktiles; kt++) {
        if (kt + 1 < ktiles) stage(kt + 1, b ^ 1);
        // A fragments (split at read; VALU overlaps MFMA pipe)
        sh8 ah[4], al[4];
#pragma unroll
        for (int mf = 0; mf < 4; mf++) {
            int row = wm * 64 + mf * 16 + l15;
            int s0 = l4 * 2;
            f32x4 a0 = *(const f32x4*)&Afs[b][row * 32 + ((s0 ^ (row & 7)) << 2)];
            f32x4 a1 = *(const f32x4*)&Afs[b][row * 32 + (((s0 + 1) ^ (row & 7)) << 2)];
            split8(a0, a1, ah[mf], al[mf]);
        }
#pragma unroll
        for (int nf = 0; nf < NF; nf++) {
            int col = wn * (NF * 16) + nf * 16 + l15;
            int sh = l4 ^ (col & 7);
            sh8 bh = *(const sh8*)&Bs[b][col * 64 + (sh << 3)];
            sh8 bl = *(const sh8*)&Bs[b][col * 64 + ((sh ^ 4) << 3)];
#pragma unroll
            for (int mf = 0; mf < 4; mf++) {
                f32x4 c = acc[mf][nf];
                c = __builtin_amdgcn_mfma_f32_16x16x32_bf16(ah[mf], bh, c, 0, 0, 0);
                c = __builtin_amdgcn_mfma_f32_16x16x32_bf16(ah[mf], bl, c, 0, 0, 0);
                c = __builtin_amdgcn_mfma_f32_16x16x32_bf16(al[mf], bh, c, 0, 0, 0);
                acc[mf][nf] = c;
            }
        }
        __syncthreads();   // drains vmcnt (prefetch t+1) + all reads of buf b
        b ^= 1;
    }
#pragma unroll
    for (int mf = 0; mf < 4; mf++)
#pragma unroll
        for (int r = 0; r < 4; r++) {
            long gm = m0 + wm * 64 + mf * 16 + l4 * 4 + r;
            if (gm >= M) continue;
#pragma unroll
            for (int nf = 0; nf < NF; nf++) {
                int gc = n0 + wn * (NF * 16) + nf * 16 + l15;
                if (gc < N) C[gm * (size_t)N + gc] = acc[mf][nf][r] + (bias ? bias[gc] : 0.f);
            }
        }
}

// ------------------------------------------------------------------
// fused FF with split-bf16 MFMA (unchanged; verified twice)
// ------------------------------------------------------------------
__global__ __launch_bounds__(256, 2) void k_ff_mfma(const float* __restrict__ x,
                                                    const short* __restrict__ W1h, const short* __restrict__ W1l,
                                                    const float* __restrict__ bf1,
                                                    const short* __restrict__ W2h, const short* __restrict__ W2l,
                                                    const float* __restrict__ bf2,
                                                    float* __restrict__ out, int n) {
    __shared__ short lds[36864];
    short* Hh = lds;
    short* Hl = lds + 9216;
    short* w1h = lds + 18432;
    short* w1l = lds + 23040;
    short* w2h = lds + 27648;
    short* w2l = lds + 32256;
    int tid = threadIdx.x;
    int wave = tid >> 6, lane = tid & 63;
    int wm = wave & 1, wn = wave >> 1;
    int l15 = lane & 15, l4 = lane >> 4;
    long row0 = (long)blockIdx.x * 128;
#pragma unroll
    for (int p = 0; p < 8; p++) {
        int f4 = tid + p * 256;
        int row = f4 >> 4, kq = f4 & 15;
        long gr = row0 + row;
        float4 a = {0.f, 0.f, 0.f, 0.f};
        if (gr < n) a = *(const float4*)&x[gr * 64 + kq * 4];
        unsigned short h0, h1, h2, h3, l0, l1, l2, l3;
        splitf(a.x, h0, l0); splitf(a.y, h1, l1);
        splitf(a.z, h2, l2); splitf(a.w, h3, l3);
        sh4 hv = {(short)h0, (short)h1, (short)h2, (short)h3};
        sh4 lv = {(short)l0, (short)l1, (short)l2, (short)l3};
        *(sh4*)&Hh[row * 72 + kq * 4] = hv;
        *(sh4*)&Hl[row * 72 + kq * 4] = lv;
    }
    __syncthreads();
    sh8 xh[4][2], xl[4][2];
#pragma unroll
    for (int mf = 0; mf < 4; mf++)
#pragma unroll
        for (int kf = 0; kf < 2; kf++) {
            int off = (wm * 64 + mf * 16 + l15) * 72 + kf * 32 + l4 * 8;
            xh[mf][kf] = *(const sh8*)&Hh[off];
            xl[mf][kf] = *(const sh8*)&Hl[off];
        }
    f32x4 acc2[4][2] = {};
    for (int j0 = 0; j0 < FF_DIM; j0 += 64) {
#pragma unroll
        for (int p = 0; p < 2; p++) {
            int u = tid + p * 256;
            int cj = u >> 3, kq8 = u & 7;
            *(sh8*)&w1h[cj * 72 + kq8 * 8] = *(const sh8*)&W1h[(size_t)(j0 + cj) * 64 + kq8 * 8];
            *(sh8*)&w1l[cj * 72 + kq8 * 8] = *(const sh8*)&W1l[(size_t)(j0 + cj) * 64 + kq8 * 8];
            *(sh8*)&w2h[cj * 72 + kq8 * 8] = *(const sh8*)&W2h[(size_t)cj * FF_DIM + j0 + kq8 * 8];
            *(sh8*)&w2l[cj * 72 + kq8 * 8] = *(const sh8*)&W2l[(size_t)cj * FF_DIM + j0 + kq8 * 8];
        }
        __syncthreads();
        f32x4 hacc[4][2] = {};
#pragma unroll
        for (int kf = 0; kf < 2; kf++) {
            sh8 bh[2], bl[2];
#pragma unroll
            for (int nf = 0; nf < 2; nf++) {
                int off = (wn * 32 + nf * 16 + l15) * 72 + kf * 32 + l4 * 8;
                bh[nf] = *(const sh8*)&w1h[off];
                bl[nf] = *(const sh8*)&w1l[off];
            }
#pragma unroll
            for (int mf = 0; mf < 4; mf++)
#pragma unroll
                for (int nf = 0; nf < 2; nf++) {
                    f32x4 c = hacc[mf][nf];
                    c = __builtin_amdgcn_mfma_f32_16x16x32_bf16(xh[mf][kf], bh[nf], c, 0, 0, 0);
                    c = __builtin_amdgcn_mfma_f32_16x16x32_bf16(xh[mf][kf], bl[nf], c, 0, 0, 0);
                    c = __builtin_amdgcn_mfma_f32_16x16x32_bf16(xl[mf][kf], bh[nf], c, 0, 0, 0);
                    hacc[mf][nf] = c;
                }
        }
#pragma unroll
        for (int mf = 0; mf < 4; mf++)
#pragma unroll
            for (int nf = 0; nf < 2; nf++) {
                int col = wn * 32 + nf * 16 + l15;
                float b1v = bf1[j0 + col];
#pragma unroll
                for (int r = 0; r < 4; r++) {
                    int row = wm * 64 + mf * 16 + l4 * 4 + r;
                    float v = fmaxf(hacc[mf][nf][r] + b1v, 0.f);
                    unsigned short h, l;
                    splitf(v, h, l);
                    Hh[row * 72 + col] = (short)h;
                    Hl[row * 72 + col] = (short)l;
                }
            }
        __syncthreads();
#pragma unroll
        for (int kf = 0; kf < 2; kf++) {
            sh8 ah[4], alv[4], bh[2], bl[2];
#pragma unroll
            for (int mf = 0; mf < 4; mf++) {
                int off = (wm * 64 + mf * 16 + l15) * 72 + kf * 32 + l4 * 8;
                ah[mf] = *(const sh8*)&Hh[off];
                alv[mf] = *(const sh8*)&Hl[off];
            }
#pragma unroll
            for (int nf = 0; nf < 2; nf++) {
                int off = (wn * 32 + nf * 16 + l15) * 72 + kf * 32 + l4 * 8;
                bh[nf] = *(const sh8*)&w2h[off];
                bl[nf] = *(const sh8*)&w2l[off];
            }
#pragma unroll
            for (int mf = 0; mf < 4; mf++)
#pragma unroll
                for (int nf = 0; nf < 2; nf++) {
                    f32x4 c = acc2[mf][nf];
                    c = __builtin_amdgcn_mfma_f32_16x16x32_bf16(ah[mf], bh[nf], c, 0, 0, 0);
                    c = __builtin_amdgcn_mfma_f32_16x16x32_bf16(ah[mf], bl[nf], c, 0, 0, 0);
                    c = __builtin_amdgcn_mfma_f32_16x16x32_bf16(alv[mf], bh[nf], c, 0, 0, 0);
                    acc2[mf][nf] = c;
                }
        }
        __syncthreads();
    }
#pragma unroll
    for (int mf = 0; mf < 4; mf++)
#pragma unroll
        for (int r = 0; r < 4; r++) {
            long gr = row0 + wm * 64 + mf * 16 + l4 * 4 + r;
            if (gr >= n) continue;
#pragma unroll
            for (int nf = 0; nf < 2; nf++) {
                int gc = wn * 32 + nf * 16 + l15;
                out[gr * 64 + gc] = acc2[mf][nf][r] + bf2[gc];
            }
        }
}

// ------------------------------------------------------------------
// per-(node,head) attention logits
// ------------------------------------------------------------------
template<int H, int D>
__global__ void k_al(const float* __restrict__ h, const float* __restrict__ a_src,
                     const float* __restrict__ a_dst, float* __restrict__ als,
                     float* __restrict__ ald, int n) {
    long w = ((long)blockIdx.x * blockDim.x + threadIdx.x) >> 6;
    int lane = threadIdx.x & 63;
    long nn = w / H;
    int hh = (int)(w % H);
    if (nn >= n) return;
    float v = 0.f, u = 0.f;
    if (lane < D) {
        float hv = h[nn * (H * D) + hh * D + lane];
        v = hv * a_src[hh * D + lane];
        u = hv * a_dst[hh * D + lane];
    }
#pragma unroll
    for (int o = 32; o > 0; o >>= 1) {
        v += __shfl_xor(v, o, 64);
        u += __shfl_xor(u, o, 64);
    }
    if (lane == 0) { als[nn * H + hh] = v; ald[nn * H + hh] = u; }
}

// ------------------------------------------------------------------
// GAT aggregation, H=4/D=64: wave per node, float4 gather (1KB/instr
// covers all 4 heads), edge-unroll-2 for MLP.
// ------------------------------------------------------------------
template<bool DO_ELU>
__global__ __launch_bounds__(256) void k_agg4(const float* __restrict__ h,
                                              const float* __restrict__ als,
                                              const float* __restrict__ ald,
                                              const float* __restrict__ bias,
                                              const int* __restrict__ rstart,
                                              const int* __restrict__ deg,
                                              const int* __restrict__ csr,
                                              float* __restrict__ out, int n) {
    int wid = (int)(((long)blockIdx.x * blockDim.x + threadIdx.x) >> 6);
    int lane = threadIdx.x & 63;
    if (wid >= n) return;
    int beg = rstart[wid], cnt = deg[wid];
    int hh = lane >> 4;                       // head owning elems lane*4..+3
    float aldv = (lane < 4) ? ald[wid * 4 + lane] : 0.f;
    const float4* h4 = (const float4*)h;
    float4 acc = {0.f, 0.f, 0.f, 0.f};
    float wsum = 0.f;
    for (int e = 0; e < cnt; e += 2) {
        bool has1 = (e + 1 < cnt);
        int s0 = csr[beg + e];
        int s1 = csr[beg + (has1 ? e + 1 : e)];
        float4 h0 = h4[(size_t)s0 * 64 + lane];
        float4 h1 = h4[(size_t)s1 * 64 + lane];
        float w0 = 0.f, w1 = 0.f;
        if (lane < 4) {
            float lg = als[s0 * 4 + lane] + aldv;
            lg = (lg > 0.f) ? lg : 0.2f * lg;
            w0 = __expf(lg);
            if (has1) {
                float lg1 = als[s1 * 4 + lane] + aldv;
                lg1 = (lg1 > 0.f) ? lg1 : 0.2f * lg1;
                w1 = __expf(lg1);
            }
            wsum += w0 + w1;
        }
        float w0b = __shfl(w0, hh, 64);
        float w1b = __shfl(w1, hh, 64);
        acc.x += w0b * h0.x + w1b * h1.x;
        acc.y += w0b * h0.y + w1b * h1.y;
        acc.z += w0b * h0.z + w1b * h1.z;
        acc.w += w0b * h0.w + w1b * h1.w;
    }
    float ws = __shfl(wsum, hh, 64) + 1e-16f;
    float4 bv = *(const float4*)&bias[lane * 4];
    float4 o;
    o.x = acc.x / ws + bv.x; o.y = acc.y / ws + bv.y;
    o.z = acc.z / ws + bv.z; o.w = acc.w / ws + bv.w;
    if (DO_ELU) {
        o.x = (o.x > 0.f) ? o.x : expm1f(o.x);
        o.y = (o.y > 0.f) ? o.y : expm1f(o.y);
        o.z = (o.z > 0.f) ? o.z : expm1f(o.z);
        o.w = (o.w > 0.f) ? o.w : expm1f(o.w);
    }
    *(float4*)&out[(size_t)wid * 256 + lane * 4] = o;
}

// ------------------------------------------------------------------
// GAT aggregation, H=1/D=64: wave per node, 4 edges/iter
// (16-lane float4 groups; per-group redundant weight compute)
// ------------------------------------------------------------------
template<bool DO_ELU>
__global__ __launch_bounds__(256) void k_agg1_64(const float* __restrict__ h,
                                                 const float* __restrict__ als,
                                                 const float* __restrict__ ald,
                                                 const float* __restrict__ bias,
                                                 const int* __restrict__ rstart,
                                                 const int* __restrict__ deg,
                                                 const int* __restrict__ csr,
                                                 float* __restrict__ out, int n) {
    int wid = (int)(((long)blockIdx.x * blockDim.x + threadIdx.x) >> 6);
    int lane = threadIdx.x & 63;
    if (wid >= n) return;
    int beg = rstart[wid], cnt = deg[wid];
    int g = lane >> 4, el = lane & 15;
    float aldv = ald[wid];
    const float4* h4 = (const float4*)h;
    float4 acc = {0.f, 0.f, 0.f, 0.f};
    float sw = 0.f;
    for (int e = 0; e < cnt; e += 4) {
        int eg = e + g;
        bool act = eg < cnt;
        int s = csr[beg + (act ? eg : cnt - 1)];
        float4 hv = h4[(size_t)s * 16 + el];
        float lg = als[s] + aldv;
        lg = (lg > 0.f) ? lg : 0.2f * lg;
        float w = act ? __expf(lg) : 0.f;
        sw += w;
        acc.x += w * hv.x; acc.y += w * hv.y;
        acc.z += w * hv.z; acc.w += w * hv.w;
    }
    // reduce across the 4 edge-groups (lanes 16 apart)
#pragma unroll
    for (int o = 16; o < 64; o <<= 1) {
        sw += __shfl_xor(sw, o, 64);
        acc.x += __shfl_xor(acc.x, o, 64);
        acc.y += __shfl_xor(acc.y, o, 64);
        acc.z += __shfl_xor(acc.z, o, 64);
        acc.w += __shfl_xor(acc.w, o, 64);
    }
    if (lane < 16) {
        float ws = sw + 1e-16f;
        float4 bv = *(const float4*)&bias[lane * 4];
        float4 o;
        o.x = acc.x / ws + bv.x; o.y = acc.y / ws + bv.y;
        o.z = acc.z / ws + bv.z; o.w = acc.w / ws + bv.w;
        if (DO_ELU) {
            o.x = (o.x > 0.f) ? o.x : expm1f(o.x);
            o.y = (o.y > 0.f) ? o.y : expm1f(o.y);
            o.z = (o.z > 0.f) ? o.z : expm1f(o.z);
            o.w = (o.w > 0.f) ? o.w : expm1f(o.w);
        }
        *(float4*)&out[(size_t)wid * 64 + lane * 4] = o;
    }
}

// ------------------------------------------------------------------
// GAT aggregation, H=1/D=25 (ADT head): wave per node, 2 edges/iter
// ------------------------------------------------------------------
__global__ __launch_bounds__(256) void k_agg1_25(const float* __restrict__ h,
                                                 const float* __restrict__ als,
                                                 const float* __restrict__ ald,
                                                 const float* __restrict__ bias,
                                                 const int* __restrict__ rstart,
                                                 const int* __restrict__ deg,
                                                 const int* __restrict__ csr,
                                                 float* __restrict__ out, int n) {
    int wid = (int)(((long)blockIdx.x * blockDim.x + threadIdx.x) >> 6);
    int lane = threadIdx.x & 63;
    if (wid >= n) return;
    int beg = rstart[wid], cnt = deg[wid];
    int g = lane >> 5, el = lane & 31;
    float aldv = ald[wid];
    float acc = 0.f, sw = 0.f;
    for (int e = 0; e < cnt; e += 2) {
        int eg = e + g;
        bool act = eg < cnt;
        int s = csr[beg + (act ? eg : cnt - 1)];
        float hv = (el < 25) ? h[(size_t)s * 25 + el] : 0.f;
        float lg = als[s] + aldv;
        lg = (lg > 0.f) ? lg : 0.2f * lg;
        float w = act ? __expf(lg) : 0.f;
        sw += w;
        acc += w * hv;
    }
    sw += __shfl_xor(sw, 32, 64);
    acc += __shfl_xor(acc, 32, 64);
    if (lane < 25) out[(size_t)wid * 25 + lane] = acc / (sw + 1e-16f) + bias[lane];
}

// ------------------------------------------------------------------
// residual + LayerNorm (64-dim rows, wave per row)
// ------------------------------------------------------------------
__global__ void k_ln(const float* __restrict__ x, const float* __restrict__ y,
                     const float* __restrict__ g, const float* __restrict__ b,
                     float* __restrict__ out, int n) {
    long w = ((long)blockIdx.x * blockDim.x + threadIdx.x) >> 6;
    int lane = threadIdx.x & 63;
    if (w >= n) return;
    float v = x[w * 64 + lane] + y[w * 64 + lane];
    float s = v;
#pragma unroll
    for (int o = 32; o > 0; o >>= 1) s += __shfl_xor(s, o, 64);
    float mu = s * (1.f / 64.f);
    float dv = v - mu;
    float q = dv * dv;
#pragma unroll
    for (int o = 32; o > 0; o >>= 1) q += __shfl_xor(q, o, 64);
    float var = q * (1.f / 64.f);
    out[w * 64 + lane] = dv * rsqrtf(var + EPSV) * g[lane] + b[lane];
}

// ------------------------------------------------------------------
extern "C" void kernel_launch(void* const* d_in, const int* in_sizes, int n_in,
                              void* d_out, int out_size, void* d_ws, size_t ws_size,
                              hipStream_t stream) {
    const float* x = (const float*)d_in[0];
    const int* esrc = (const int*)d_in[1];
    const int* edst = (const int*)d_in[2];
    const float* W1 = (const float*)d_in[3];
    const float* as1 = (const float*)d_in[4];
    const float* ad1 = (const float*)d_in[5];
    const float* b1 = (const float*)d_in[6];
    const float* W2 = (const float*)d_in[7];
    const float* as2 = (const float*)d_in[8];
    const float* ad2 = (const float*)d_in[9];
    const float* b2 = (const float*)d_in[10];
    // t_Wq/t_Wk/t_bq/t_bk (11,12,14,15) dead: seq_len==1 -> attn = v
    const float* tWv = (const float*)d_in[13];
    const float* tbv = (const float*)d_in[16];
    const float* tWo = (const float*)d_in[17];
    const float* tbo = (const float*)d_in[18];
    const float* tg1 = (const float*)d_in[19];
    const float* tb1 = (const float*)d_in[20];
    const float* tWf1 = (const float*)d_in[21];
    const float* tbf1 = (const float*)d_in[22];
    const float* tWf2 = (const float*)d_in[23];
    const float* tbf2 = (const float*)d_in[24];
    const float* tg2 = (const float*)d_in[25];
    const float* tb2 = (const float*)d_in[26];
    const float* W3 = (const float*)d_in[27];
    const float* as3 = (const float*)d_in[28];
    const float* ad3 = (const float*)d_in[29];
    const float* b3 = (const float*)d_in[30];

    const int n = N_NODES;
    const int E = in_sizes[1];
    const int ET = E + n;

    // ---- workspace layout ----
    float* fw = (float*)d_ws;
    float* h1 = fw;                        // [n,256]
    float* agg1 = fw + 12800000;           // [n,256]
    float* bufA = fw + 25600000;           // [n,64]
    float* bufB = fw + 28800000;
    float* bufC = fw + 32000000;
    float* bufD = fw + 35200000;
    float* als = fw + 38400000;            // [n,4]
    float* ald = fw + 38600000;
    float* bc = fw + 38800000;             // [64]
    int* deg = (int*)(fw + 38800064);
    int* rstart = deg + 50016;
    int* cursor = rstart + 50016;
    int* part = cursor + 50016;
    int* csr = part + 64;                  // [E+n] <= 700000
    short* sbase = (short*)(csr + 700000);
    short* w1th = sbase;                   // [256][2048]
    short* w1tl = w1th + 524288;
    short* w2th = w1tl + 524288;           // [64][256]
    short* w2tl = w2th + 16384;
    short* w3th = w2tl + 16384;            // [64][64] (cols 25..63 zero)
    short* w3tl = w3th + 4096;
    short* wcth = w3tl + 4096;             // [64][64] combined attn
    short* wctl = wcth + 4096;
    const size_t WFS = 131072;             // 2048*64
    short* wf1h = wctl + 4096;             // [l][2048][64]
    short* wf1l = wf1h + 2 * WFS;
    short* wf2h = wf1l + 2 * WFS;          // [l][64][2048]
    short* wf2l = wf2h + 2 * WFS;
    float* h3 = h1;                        // [n,25] reuses h1 (dead by then)

    float* outAdt = (float*)d_out;                 // [n,25]
    float* outFused = outAdt + (size_t)n * 25;     // [n,64]

    // ---- CSR build ----
    k_zero_i32<<<(150048 + 255) / 256, 256, 0, stream>>>(deg, 150048);
    k_hist<<<(ET + 255) / 256, 256, 0, stream>>>(edst, deg, E, n);
    int nsb = (n + SCAN_B - 1) / SCAN_B;
    k_scan1<<<nsb, SCAN_B, 0, stream>>>(deg, rstart, part, n);
    k_scan2<<<1, 64, 0, stream>>>(part, nsb);
    k_scan3<<<(n + 255) / 256, 256, 0, stream>>>(rstart, part, n);
    k_scatter<<<(ET + 255) / 256, 256, 0, stream>>>(esrc, edst, rstart, cursor, csr, E, n);

    // ---- weight preprocessing ----
    k_wsplit_pad<<<(524288 + 255) / 256, 256, 0, stream>>>(W1, w1th, w1tl, IN_DIMC, 256, 2048, 256);
    k_wsplit_pad<<<(16384 + 255) / 256, 256, 0, stream>>>(W2, w2th, w2tl, 256, 64, 256, 64);
    k_wsplit_pad<<<(4096 + 255) / 256, 256, 0, stream>>>(W3, w3th, w3tl, 64, 25, 64, 64);
    for (int l = 0; l < 2; l++) {
        k_wsplit<<<(131072 + 255) / 256, 256, 0, stream>>>(tWf1 + (size_t)l * 64 * FF_DIM,
                                                           wf1h + l * WFS, wf1l + l * WFS, 64, FF_DIM);
        k_wsplit<<<(131072 + 255) / 256, 256, 0, stream>>>(tWf2 + (size_t)l * FF_DIM * 64,
                                                           wf2h + l * WFS, wf2l + l * WFS, FF_DIM, 64);
    }

    // ---- GAT layer 1 (heads=4, D=64) ----
    k_gemm_p<4><<<dim3((n + 127) / 128, 2), 256, 0, stream>>>(x, w1th, w1tl, nullptr, h1, n, 256, IN_DIMC, 2048);
    k_al<4, 64><<<n, 256, 0, stream>>>(h1, as1, ad1, als, ald, n);
    k_agg4<true><<<(n + 3) / 4, 256, 0, stream>>>(h1, als, ald, b1, rstart, deg, csr, agg1, n);

    // ---- GAT layer 2 (heads=1, D=64) ----
    k_gemm_p<2><<<dim3((n + 127) / 128, 1), 256, 0, stream>>>(agg1, w2th, w2tl, nullptr, bufA, n, 64, 256, 256);
    k_al<1, 64><<<(n + 3) / 4, 256, 0, stream>>>(bufA, as2, ad2, als, ald, n);
    k_agg1_64<true><<<(n + 3) / 4, 256, 0, stream>>>(bufA, als, ald, b2, rstart, deg, csr, bufB, n);

    // ---- Transformer encoder x2 (attn = x@(Wv@Wo) + (bv@Wo+bo)) ----
    float* xin = bufB;
    for (int l = 0; l < 2; l++) {
        k_wcomb<<<16, 256, 0, stream>>>(tWv + (size_t)l * 4096, tbv + (size_t)l * 64,
                                        tWo + (size_t)l * 4096, tbo + (size_t)l * 64,
                                        wcth, wctl, bc);
        k_gemm_p<2><<<dim3((n + 127) / 128, 1), 256, 0, stream>>>(xin, wcth, wctl, bc, bufD, n, 64, 64, 64);
        k_ln<<<(n + 3) / 4, 256, 0, stream>>>(xin, bufD, tg1 + (size_t)l * 64, tb1 + (size_t)l * 64, bufA, n);
        k_ff_mfma<<<(n + 127) / 128, 256, 0, stream>>>(bufA, wf1h + l * WFS, wf1l + l * WFS,
                                                       tbf1 + (size_t)l * FF_DIM,
                                                       wf2h + l * WFS, wf2l + l * WFS,
                                                       tbf2 + (size_t)l * 64, bufC, n);
        float* xout = (l == 1) ? outFused : bufB;
        k_ln<<<(n + 3) / 4, 256, 0, stream>>>(bufA, bufC, tg2 + (size_t)l * 64, tb2 + (size_t)l * 64, xout, n);
        xin = xout;
    }

    // ---- GAT ADT head (heads=1, D=25, no ELU) ----
    k_gemm_p<2><<<dim3((n + 127) / 128, 1), 256, 0, stream>>>(outFused, w3th, w3tl, nullptr, h3, n, 25, 64, 64);
    k_al<1, 25><<<(n + 3) / 4, 256, 0, stream>>>(h3, as3, ad3, als, ald, n);
    k_agg1_25<<<(n + 3) / 4, 256, 0, stream>>>(h3, als, ald, b3, rstart, deg, csr, outAdt, n);
}